// Round 6
// baseline (4030.328 us; speedup 1.0000x reference)
//
#include <hip/hip_runtime.h>
#include <math.h>

#define HH 160
#define WW 180
#define HWSZ (HH*WW)
#define BB 8
#define BB2 16                           // both branches merged in z
#define P1 ((size_t)BB*HWSZ)             // 230400 (one branch, one plane)
#define PE2 ((size_t)BB2*32*HWSZ)        // merged 32-ch plane set (both branches)

typedef unsigned short u16;
typedef unsigned long long ull;
typedef __attribute__((ext_vector_type(8))) short short8;
typedef __attribute__((ext_vector_type(2))) unsigned long long ull2;
typedef __attribute__((ext_vector_type(4))) float floatx4;

struct Ptrs16 { const float* p[16]; };

// ---------------- bf16 helpers ----------------
__device__ __forceinline__ u16 f2b(float f) {
  unsigned u = __builtin_bit_cast(unsigned, f);
  unsigned r = (u + 0x7fffu + ((u >> 16) & 1u)) >> 16;
  return (u16)r;
}
__device__ __forceinline__ float b2f(u16 h) {
  return __builtin_bit_cast(float, ((unsigned)h) << 16);
}

// ---------------- activation (eq. 33), delta = 0.01 ----------------
__device__ __forceinline__ float actf(float x) {
  float q = x*x*25.0f + 0.5f*x + 0.0025f;
  float r = fmaxf(x, 0.0f);
  return (fabsf(x) > 0.01f) ? r : q;
}
__device__ __forceinline__ float actdf(float x) {
  float q = x*50.0f + 0.5f;
  float r = (x > 0.0f) ? 1.0f : 0.0f;
  return (fabsf(x) > 0.01f) ? r : q;
}

// ---------------- weight prep, all 12 slots in one dispatch ----------------
// fp32 [o][c][9] -> bf16 [tap][nt][plane(r,i)][o16][c32], 18432 u16 per slot.
// -Wi is derived in-kernel by sign-bit XOR (R10-verified numerically exact).
__global__ void prep_all(Ptrs16 ps, u16* __restrict__ dst0) {
  const int rIdx[12] = {2,4,6,6,4,2,10,12,14,14,12,10};
  const int bwdF[12] = {0,0,0,1,1,1,0,0,0,1,1,1};
  int slot = blockIdx.x / 36;
  int idx = (blockIdx.x % 36)*256 + threadIdx.x;
  if (idx >= 9*32*32) return;
  const float* wr = ps.p[rIdx[slot]];
  const float* wi = ps.p[rIdx[slot]+1];
  u16* dst = dst0 + (size_t)slot*18432;
  int tap = idx >> 10; int rem = idx & 1023; int o = rem >> 5; int c = rem & 31;
  int s = bwdF[slot] ? ((c*32 + o)*9 + (8 - tap)) : ((o*32 + c)*9 + tap);
  float vr = wr[s], vi = wi[s];
  int nt = o >> 4, m = o & 15;
  size_t base = (((size_t)tap*2 + nt)*2*16 + (size_t)m)*32 + c;
  dst[base]       = f2b(vr);
  dst[base + 512] = f2b(vi);
}

// ---------------- MFMA complex conv 32->32, 3x3 SAME, implicit GEMM -----------------
// NHWC bf16: addr = ((b*HH+y)*WW+x)*32 + ch, R at 0, I at +PE2. b in [0,16): branch=b>>3.
// T14 PIPELINE: each block owns a 32x20 strip = 5 y-tiles of 32x4; rolling 12-row
// circular LDS buffer (row r -> slot r%12). Per tile: issue next tile's 4 new halo
// rows into REGS -> compute current tile from LDS -> ds_write regs -> ONE barrier.
// Read slots (4t..4t+5)%12 and write slots (4t+6..4t+9)%12 are disjoint, so the
// global-load latency hides entirely under the tile's MFMA+epilogue.
// LDS 52224 B -> 3 blocks/CU; grid 768 = exactly 3/CU, single round.
// Bank spread via T2 XOR swizzle: byteaddr ^= ((B>>7)&7)<<4 at write AND read
// (16B chunks move whole; stg 128B-aligned; involution in-bounds; R3: conflicts OK).
// R4 BUGFIX: prologue stages 12 prows x 136 = 1632 chunks (was 1536 -> garbage in
// I-plane row o=5 cols 10..33 -> absmax 0.84).
// Weights: Wr/Wi in-loop loads (36 KB slot = L1/L2-resident), nWi by register XOR.
// OPERAND-SWAPPED MFMA: A=weights (M=och), B=pixels (N=px) -> D row=och, col=px.
// MODE: 0 plain, 1 act, 2 cmul by actdf(der), 3 channel-norm normalize (fused)
template<int MODE>
__global__ __launch_bounds__(256, 3)
void conv_mfma(const u16* __restrict__ inb, const u16* __restrict__ wbA,
               const u16* __restrict__ wbB, u16* __restrict__ outb,
               const u16* __restrict__ derb,
               const float* __restrict__ thrA, const float* __restrict__ thrB)
{
  __shared__ alignas(128) u16 stg[2*12*34*32];   // 52224 B, plane-major, 12 row slots
  const int tid = threadIdx.x;
  const int lane = tid & 63, wv = tid >> 6;      // wv in [0,4): one output row per wave
  const int x0 = blockIdx.x * 32, y0 = blockIdx.y * 20, b = blockIdx.z;
  const u16* wb = (b < BB) ? wbA : wbB;
  const int m = lane & 15, q = lane >> 4;

  // ---- prologue: stage halo rows o=0..5 (slots 0..5), 1632 16B chunks ----
  for (int j = tid; j < 1632; j += 256) {
    int prow = j / 136; int rem = j - prow*136;
    int col = rem >> 2, chq = rem & 3;
    int plane = prow / 6, o = prow - plane*6;
    int gy = y0 - 1 + o, gx = x0 - 1 + col;
    ull v0 = 0, v1 = 0;
    if (gy >= 0 && gy < HH && gx >= 0 && gx < WW) {
      const ull* src = (const ull*)(inb + (size_t)plane*PE2
                                    + (((size_t)b*HH + gy)*WW + gx)*32 + chq*8);
      v0 = src[0]; v1 = src[1];
    }
    int B = plane*26112 + (o*34 + col)*64 + chq*16;
    B ^= ((B >> 7) & 7) << 4;
    ull* dst = (ull*)((char*)stg + B);
    dst[0] = v0; dst[1] = v1;
  }
  __syncthreads();

  for (int t = 0; t < 5; ++t) {
    const int t4 = t*4;
    const bool pref = (t < 4);

    // ---- issue next-tile halo loads to regs (rows o=4t+6..4t+9, gy=y0+4t+5+k) ----
    ull va0[5], va1[5];
    if (pref) {
#pragma unroll
      for (int it = 0; it < 5; ++it) {
        va0[it] = 0; va1[it] = 0;
        int j = tid + it*256;
        if (j < 1088) {
          int prow = j / 136; int rem = j - prow*136;
          int col = rem >> 2, chq = rem & 3;
          int k = prow >> 1, plane = prow & 1;
          int gy = y0 + t4 + 5 + k, gx = x0 - 1 + col;
          if (gy < HH && gx >= 0 && gx < WW) {
            const ull* src = (const ull*)(inb + (size_t)plane*PE2
                                          + (((size_t)b*HH + gy)*WW + gx)*32 + chq*8);
            va0[it] = src[0]; va1[it] = src[1];
          }
        }
      }
      __builtin_amdgcn_sched_barrier(0);   // pin load issue above compute
    }

    // ---- compute tile t from LDS ----
    floatx4 accr[2][2], acci[2][2];   // [seg][nt]
#pragma unroll
    for (int s = 0; s < 2; ++s)
#pragma unroll
      for (int nt = 0; nt < 2; ++nt) {
        accr[s][nt] = (floatx4){0.f,0.f,0.f,0.f};
        acci[s][nt] = (floatx4){0.f,0.f,0.f,0.f};
      }

#pragma unroll
    for (int tap = 0; tap < 9; ++tap) {
      const int ky = tap / 3, kx = tap - ky*3;
      int ro = t4 + wv + ky;                 // row o in [0,22)
      int slot = (ro >= 12) ? ro - 12 : ro;  // row -> circular slot
      short8 Pr[2], Pi[2];                   // pixel fragments: B[k=ch][n=px]
#pragma unroll
      for (int s = 0; s < 2; ++s) {
        int col = s*16 + m + kx;
        int BR = (slot*34 + col)*64 + q*16;  // R-plane linear byte addr
        int BI = BR + 26112;                 // + plane stride
        BR ^= ((BR >> 7) & 7) << 4;
        BI ^= ((BI >> 7) & 7) << 4;
        const ull* pR = (const ull*)((const char*)stg + BR);
        const ull* pI = (const ull*)((const char*)stg + BI);
        ull2 vr; vr.x = pR[0]; vr.y = pR[1];
        ull2 vi; vi.x = pI[0]; vi.y = pI[1];
        Pr[s] = __builtin_bit_cast(short8, vr);
        Pi[s] = __builtin_bit_cast(short8, vi);
      }
#pragma unroll
      for (int nt = 0; nt < 2; ++nt) {
        const u16* pw = wb + (size_t)(tap*2 + nt)*1024 + (size_t)m*32 + q*8;
        short8 Wr = *(const short8*)pw;           // weight frags: A[m=och][k=ch]
        short8 Wi = *(const short8*)(pw + 512);
        ull2 wx = __builtin_bit_cast(ull2, Wi);
        wx.x ^= 0x8000800080008000ULL;
        wx.y ^= 0x8000800080008000ULL;
        short8 nWi = __builtin_bit_cast(short8, wx);
#pragma unroll
        for (int s = 0; s < 2; ++s) {
          accr[s][nt] = __builtin_amdgcn_mfma_f32_16x16x32_bf16(Wr,  Pr[s], accr[s][nt], 0, 0, 0);
          accr[s][nt] = __builtin_amdgcn_mfma_f32_16x16x32_bf16(nWi, Pi[s], accr[s][nt], 0, 0, 0);
          acci[s][nt] = __builtin_amdgcn_mfma_f32_16x16x32_bf16(Wr,  Pi[s], acci[s][nt], 0, 0, 0);
          acci[s][nt] = __builtin_amdgcn_mfma_f32_16x16x32_bf16(Wi,  Pr[s], acci[s][nt], 0, 0, 0);
        }
      }
    }

    // ---- write staged regs to LDS (slots disjoint from this tile's reads) ----
    if (pref) {
#pragma unroll
      for (int it = 0; it < 5; ++it) {
        int j = tid + it*256;
        if (j < 1088) {
          int prow = j / 136; int rem = j - prow*136;
          int col = rem >> 2, chq = rem & 3;
          int k = prow >> 1, plane = prow & 1;
          int s = t4 + 6 + k; if (s >= 12) s -= 12;
          int B = plane*26112 + (s*34 + col)*64 + chq*16;
          B ^= ((B >> 7) & 7) << 4;
          ull* dst = (ull*)((char*)stg + B);
          dst[0] = va0[it]; dst[1] = va1[it];
        }
      }
    }

    // ---- direct epilogue: lane holds px = x0+s*16+m, och = nt*16+q*4+r in regs ----
    const int y = y0 + t4 + wv;
#pragma unroll
    for (int s = 0; s < 2; ++s) {
      int x = x0 + s*16 + m;
      bool ok = (x < WW);
      float invn = 1.0f;
      if constexpr (MODE == 3) {
        float ss = 0.f;
#pragma unroll
        for (int nt = 0; nt < 2; ++nt)
#pragma unroll
          for (int r = 0; r < 4; ++r)
            ss += accr[s][nt][r]*accr[s][nt][r] + acci[s][nt][r]*acci[s][nt][r];
        ss += __shfl_xor(ss, 16, 64);    // sum over q (lane bits 4,5): full 32-och norm
        ss += __shfl_xor(ss, 32, 64);
        float thr = (b < BB ? thrA : thrB)[0];
        invn = 1.0f / fmaxf(sqrtf(ss), thr);
      }
      size_t pxbase = (((size_t)b*HH + y)*WW + x)*32;
#pragma unroll
      for (int nt = 0; nt < 2; ++nt) {
        size_t gb = pxbase + nt*16 + q*4;
        ull dR = 0, dI = 0;
        if constexpr (MODE == 2) {
          if (ok) { dR = *(const ull*)(derb + gb); dI = *(const ull*)(derb + PE2 + gb); }
        }
        ull vR = 0, vI = 0;
#pragma unroll
        for (int r = 0; r < 4; ++r) {
          float pr = accr[s][nt][r], pi = acci[s][nt][r];
          if constexpr (MODE == 1) { pr = actf(pr); pi = actf(pi); }
          if constexpr (MODE == 3) { pr *= invn; pi *= invn; }
          if constexpr (MODE == 2) {
            float dr = actdf(b2f((u16)(dR >> (16*r))));
            float di = actdf(b2f((u16)(dI >> (16*r))));
            float nr = pr*dr - pi*di;
            pi = pr*di + pi*dr; pr = nr;
          }
          vR |= (ull)f2b(pr) << (16*r);
          vI |= (ull)f2b(pi) << (16*r);
        }
        if (ok) {
          *(ull*)(outb + gb)       = vR;
          *(ull*)(outb + PE2 + gb) = vI;
        }
      }
    }

    __syncthreads();   // staged writes visible before tile t+1 reads them
  }
}

// ---------------- layer-1 forward: complex conv 1->32 + act, planar fp32 -> NHWC bf16
// 8x8 px tile; 256 threads: og = tid&3 (8 och each), px = tid>>2 (lx=px&7, ly=px>>3).
__global__ __launch_bounds__(256)
void l1fwd(const float* __restrict__ xall,
           const float* __restrict__ wrA, const float* __restrict__ wiA,
           const float* __restrict__ wrB, const float* __restrict__ wiB,
           u16* __restrict__ outb)
{
  __shared__ float hR[10][12], hI[10][12];
  __shared__ float wt[9][32][2];
  const int tid = threadIdx.x;
  const int og = tid & 3, px = tid >> 2;
  const int lx = px & 7, ly = px >> 3;
  const int x0 = blockIdx.x*8, y0 = blockIdx.y*8, b = blockIdx.z;
  const int branch = b >> 3, img = b & 7;
  const float* wr = branch ? wrB : wrA;
  const float* wi = branch ? wiB : wiA;
  const float* xp = xall + (size_t)branch*2*P1 + (size_t)img*HWSZ;

  for (int j = tid; j < 576; j += 256) {
    int tap = j >> 6; int rem = j & 63; int o = rem >> 1, ri = rem & 1;
    wt[tap][o][ri] = ri ? wi[o*9+tap] : wr[o*9+tap];
  }
  for (int j = tid; j < 200; j += 256) {
    int plane = j / 100; int pos = j - plane*100;
    int yy = pos / 10, xx = pos - yy*10;
    int gy = y0 - 1 + yy, gx = x0 - 1 + xx;
    float v = 0.f;
    if (gy >= 0 && gy < HH && gx >= 0 && gx < WW)
      v = xp[(size_t)plane*P1 + (size_t)gy*WW + gx];
    (plane ? hI : hR)[yy][xx] = v;
  }
  __syncthreads();

  float accR[8], accI[8];
#pragma unroll
  for (int o = 0; o < 8; ++o) { accR[o] = 0.f; accI[o] = 0.f; }
#pragma unroll
  for (int tap = 0; tap < 9; ++tap) {
    int ky = tap/3, kx = tap - ky*3;
    float ar = hR[ly+ky][lx+kx], ai = hI[ly+ky][lx+kx];
#pragma unroll
    for (int o = 0; o < 8; ++o) {
      float wrv = wt[tap][og*8+o][0], wiv = wt[tap][og*8+o][1];
      accR[o] += ar*wrv - ai*wiv;
      accI[o] += ar*wiv + ai*wrv;
    }
  }
  int gx = x0 + lx, gy = y0 + ly;
  if (gx < WW) {
    size_t base = (((size_t)b*HH + gy)*WW + gx)*32 + og*8;
    ull* dR = (ull*)(outb + base);
    ull* dI = (ull*)(outb + PE2 + base);
#pragma unroll
    for (int k = 0; k < 2; ++k) {
      ull vR = 0, vI = 0;
#pragma unroll
      for (int t = 0; t < 4; ++t) {
        vR |= (ull)f2b(actf(accR[k*4+t])) << (16*t);
        vI |= (ull)f2b(actf(accI[k*4+t])) << (16*t);
      }
      dR[k] = vR; dI[k] = vI;
    }
  }
}

// ---------------- layer-1 backward: complex convT 32->1, NHWC bf16 -> planar fp32 ----
// 8x8 px tile; 256 threads: cg = tid&3 (8 ch each), px = tid>>2; quad shfl reduce.
__global__ __launch_bounds__(256)
void l1bwd(const u16* __restrict__ gb,
           const float* __restrict__ wrA, const float* __restrict__ wiA,
           const float* __restrict__ wrB, const float* __restrict__ wiB,
           float* __restrict__ outp)
{
  __shared__ alignas(16) u16 stg[2*100*32];   // [plane][pos10x10][ch32] = 12.5 KB
  __shared__ float wt[32][9][2];
  const int tid = threadIdx.x;
  const int cg = tid & 3, px = tid >> 2;
  const int lx = px & 7, ly = px >> 3;
  const int x0 = blockIdx.x*8, y0 = blockIdx.y*8, b = blockIdx.z;
  const int branch = b >> 3, img = b & 7;
  const float* wr = branch ? wrB : wrA;
  const float* wi = branch ? wiB : wiA;

  for (int j = tid; j < 576; j += 256) {
    int c = j / 18; int rem = j - c*18; int tap = rem >> 1, ri = rem & 1;
    wt[c][tap][ri] = (ri ? wi : wr)[c*9 + (8-tap)];
  }
  // stage halo: 800 16B chunks (2 planes x 100 pos x 4 chq)
  for (int j = tid; j < 800; j += 256) {
    int plane = j / 400; int rem = j - plane*400;
    int pos = rem >> 2, chq = rem & 3;
    int yy = pos / 10, xx = pos - yy*10;
    int gy = y0 - 1 + yy, gx = x0 - 1 + xx;
    ull v0 = 0, v1 = 0;
    if (gy >= 0 && gy < HH && gx >= 0 && gx < WW) {
      const ull* src = (const ull*)(gb + (size_t)plane*PE2
                                    + (((size_t)b*HH + gy)*WW + gx)*32 + chq*8);
      v0 = src[0]; v1 = src[1];
    }
    ull* dst = (ull*)&stg[((size_t)plane*100 + pos)*32 + chq*8];
    dst[0] = v0; dst[1] = v1;
  }
  __syncthreads();

  float gr = 0.f, gi = 0.f;
#pragma unroll
  for (int tap = 0; tap < 9; ++tap) {
    int ky = tap/3, kx = tap - ky*3;
    int pos = (ly+ky)*10 + (lx+kx);
    const ull* pR = (const ull*)&stg[(size_t)pos*32 + cg*8];
    const ull* pI = (const ull*)&stg[(100 + (size_t)pos)*32 + cg*8];
    ull r0 = pR[0], r1 = pR[1], i0 = pI[0], i1 = pI[1];
#pragma unroll
    for (int t = 0; t < 4; ++t) {
      int c = cg*8 + t;
      float ar = b2f((u16)(r0 >> (16*t))), ai = b2f((u16)(i0 >> (16*t)));
      float wrv = wt[c][tap][0], wiv = wt[c][tap][1];
      gr += ar*wrv - ai*wiv;
      gi += ar*wiv + ai*wrv;
    }
#pragma unroll
    for (int t = 0; t < 4; ++t) {
      int c = cg*8 + 4 + t;
      float ar = b2f((u16)(r1 >> (16*t))), ai = b2f((u16)(i1 >> (16*t)));
      float wrv = wt[c][tap][0], wiv = wt[c][tap][1];
      gr += ar*wrv - ai*wiv;
      gi += ar*wiv + ai*wrv;
    }
  }
  gr += __shfl_xor(gr, 1, 64); gr += __shfl_xor(gr, 2, 64);
  gi += __shfl_xor(gi, 1, 64); gi += __shfl_xor(gi, 2, 64);

  int gx = x0 + lx, gy = y0 + ly;
  if (cg == 0 && gx < WW) {
    size_t o2 = (size_t)branch*2*P1 + (size_t)img*HWSZ + (size_t)gy*WW + gx;
    outp[o2]      = gr;
    outp[P1 + o2] = gi;
  }
}

// ---------------- DFT machinery ----------------
__global__ void gen_dft2(float2* __restrict__ Mf, float2* __restrict__ Mi, int N) {
  int idx = blockIdx.x*256 + threadIdx.x;
  if (idx >= N*N) return;
  int r = idx / N, c = idx - r*N;
  long mm = ((long)r * (long)c) % N;
  double a = 2.0 * 3.14159265358979323846 * (double)mm / (double)N;
  double cs = cos(a), sn = sin(a);
  Mf[idx] = make_float2((float)cs, (float)(-sn));
  Mi[idx] = make_float2((float)(cs/N), (float)(sn/N));
}

// row-DFT from planar x (both branches): bh over [0, 16*HH)
__global__ void dft_row_planes(const float* __restrict__ xall,
                               float2* __restrict__ out, const float2* __restrict__ M) {
  int bh = blockIdx.x;
  int v = threadIdx.x; if (v >= WW) return;
  int b2 = bh / HH, h = bh - b2*HH;
  int branch = b2 >> 3, img = b2 & 7;
  const float* rowR = xall + (size_t)branch*2*P1 + (size_t)img*HWSZ + (size_t)h*WW;
  const float* rowI = rowR + P1;
  float ar = 0.f, ai = 0.f;
  for (int w = 0; w < WW; ++w) {
    float sr = rowR[w], si = rowI[w];
    float2 m = M[w*WW + v];
    ar += sr*m.x - si*m.y;
    ai += sr*m.y + si*m.x;
  }
  out[(size_t)bh*WW + v] = make_float2(ar, ai);
}

__global__ void dft_row_c(const float2* __restrict__ in, float2* __restrict__ out,
                          const float2* __restrict__ M) {
  int bh = blockIdx.x;
  int v = threadIdx.x; if (v >= WW) return;
  const float2* row = in + (size_t)bh*WW;
  float ar = 0.f, ai = 0.f;
  for (int w = 0; w < WW; ++w) {
    float2 s = row[w];
    float2 m = M[w*WW + v];
    ar += s.x*m.x - s.y*m.y;
    ai += s.x*m.y + s.y*m.x;
  }
  out[(size_t)bh*WW + v] = make_float2(ar, ai);
}

__global__ void dft_col_c(const float2* __restrict__ in, float2* __restrict__ out,
                          const float2* __restrict__ M) {
  int bu = blockIdx.x;
  int v = threadIdx.x; if (v >= WW) return;
  int b = bu / HH, u = bu - b*HH;
  const float2* base = in + (size_t)b*HWSZ;
  float ar = 0.f, ai = 0.f;
  for (int h = 0; h < HH; ++h) {
    float2 m = M[u*HH + h];
    float2 s = base[(size_t)h*WW + v];
    ar += s.x*m.x - s.y*m.y;
    ai += s.x*m.y + s.y*m.x;
  }
  out[(size_t)bu*WW + v] = make_float2(ar, ai);
}

// col-iDFT with fused mask^2 on input element (h,v)
__global__ void dft_col_mask(const float2* __restrict__ in, float2* __restrict__ out,
                             const float2* __restrict__ M, const float* __restrict__ mask) {
  int bu = blockIdx.x;
  int v = threadIdx.x; if (v >= WW) return;
  int b = bu / HH, u = bu - b*HH;
  const float2* base = in + (size_t)b*HWSZ;
  float ar = 0.f, ai = 0.f;
  for (int h = 0; h < HH; ++h) {
    float mk = mask[h*WW + v]; float mm = mk*mk;
    float2 m = M[u*HH + h];
    float2 s = base[(size_t)h*WW + v];
    float sr = s.x*mm, si = s.y*mm;
    ar += sr*m.x - si*m.y;
    ai += sr*m.y + si*m.x;
  }
  out[(size_t)bu*WW + v] = make_float2(ar, ai);
}

// final row-iDFT fused with x update: x -= a*(gradf - ct) + bet*gr
__global__ void dft_row_update(const float2* __restrict__ in, const float2* __restrict__ M,
                               const float2* __restrict__ ctall, const float* __restrict__ grp,
                               float* __restrict__ xall,
                               const float* __restrict__ al1, const float* __restrict__ al2,
                               const float* __restrict__ be1, const float* __restrict__ be2,
                               int phase) {
  int bh = blockIdx.x;
  int v = threadIdx.x; if (v >= WW) return;
  int b2 = bh / HH, h = bh - b2*HH;
  int branch = b2 >> 3, img = b2 & 7;
  const float2* row = in + (size_t)bh*WW;
  float ar = 0.f, ai = 0.f;
  for (int w = 0; w < WW; ++w) {
    float2 s = row[w];
    float2 m = M[w*WW + v];
    ar += s.x*m.x - s.y*m.y;
    ai += s.x*m.y + s.y*m.x;
  }
  float2 ct = ctall[(size_t)bh*WW + v];
  float a   = (branch ? al2 : al1)[phase];
  float bet = (branch ? be2 : be1)[phase];
  size_t xo = (size_t)branch*2*P1 + (size_t)img*HWSZ + (size_t)h*WW + v;
  xall[xo]      -= a*(ar - ct.x) + bet*grp[xo];
  xall[P1 + xo] -= a*(ai - ct.y) + bet*grp[P1 + xo];
}

// ---------------- small pointwise kernels ----------------
__global__ void maskk_m(const float* __restrict__ k1, const float* __restrict__ k2,
                        const float* __restrict__ mask, float2* __restrict__ t) {
  int i = blockIdx.x*256 + threadIdx.x;
  if (i >= (int)(2*P1)) return;
  int branch = i >= (int)P1;
  int ii = i - branch*(int)P1;
  int b = ii / HWSZ, p = ii - b*HWSZ;
  const float* k = branch ? k2 : k1;
  float m = mask[p];
  t[i] = make_float2(m * k[(size_t)b*2*HWSZ + p], m * k[(size_t)b*2*HWSZ + HWSZ + p]);
}

__global__ void unpack_m(const float* __restrict__ x1, const float* __restrict__ x2,
                         float* __restrict__ xall) {
  int i = blockIdx.x*256 + threadIdx.x;
  if (i >= (int)(2*P1)) return;
  int branch = i >= (int)P1;
  int ii = i - branch*(int)P1;
  int b = ii / HWSZ, p = ii - b*HWSZ;
  const float* src = branch ? x2 : x1;
  size_t dst = (size_t)branch*2*P1 + (size_t)b*HWSZ + p;
  xall[dst]      = src[(size_t)b*2*HWSZ + p];
  xall[P1 + dst] = src[(size_t)b*2*HWSZ + HWSZ + p];
}

__global__ void pack_kernel(const float* __restrict__ xall, float* __restrict__ out) {
  int i = blockIdx.x*256 + threadIdx.x;
  if (i >= (int)P1) return;
  int b = i / HWSZ, p = i - b*HWSZ;
  size_t ob = (size_t)b*4*HWSZ;
  size_t x1o = (size_t)b*HWSZ + p;
  size_t x2o = 2*P1 + x1o;
  out[ob + p]          = xall[x1o];
  out[ob + HWSZ + p]   = xall[P1 + x1o];
  out[ob + 2*HWSZ + p] = xall[x2o];
  out[ob + 3*HWSZ + p] = xall[P1 + x2o];
}

// ---------------- launch ----------------
extern "C" void kernel_launch(void* const* d_in, const int* in_sizes, int n_in,
                              void* d_out, int out_size, void* d_ws, size_t ws_size,
                              hipStream_t stream) {
  (void)in_sizes; (void)n_in; (void)out_size; (void)ws_size;
  const float* x1in = (const float*)d_in[0];
  const float* x2in = (const float*)d_in[1];
  const float* k1   = (const float*)d_in[2];
  const float* k2   = (const float*)d_in[3];
  const float* mask = (const float*)d_in[4];
  Ptrs16 cw;
  for (int i = 0; i < 16; ++i) cw.p[i] = (const float*)d_in[5+i];
  const float* thr1 = (const float*)d_in[21];
  const float* thr2 = (const float*)d_in[22];
  const float* al1  = (const float*)d_in[23];
  const float* al2  = (const float*)d_in[24];
  const float* be1  = (const float*)d_in[25];
  const float* be2  = (const float*)d_in[26];
  float* out = (float*)d_out;

  // ---- workspace: bf16 region then fp32 region ----
  u16* U = (u16*)d_ws;
  size_t uoff = 0;
  auto alloc_u = [&](size_t n){ u16* p = U + uoff; uoff += (n + 15) & ~(size_t)15; return p; };
  u16* act1 = alloc_u(2*PE2);
  u16* act2 = alloc_u(2*PE2);
  u16* act3 = alloc_u(2*PE2);
  u16* w4b  = alloc_u(2*PE2);
  u16* wp0  = alloc_u(12*18432);

  float* F = (float*)(U + uoff);
  size_t off = 0;
  auto alloc_f = [&](size_t n){ float* p = F + off; off += (n + 3) & ~(size_t)3; return p; };
  float*  xall = alloc_f(4*P1);                       // [branch][plane][P1]
  float*  grp  = alloc_f(4*P1);
  float2* t1   = (float2*)alloc_f(4*P1);              // [16][HWSZ] complex
  float2* t2   = (float2*)alloc_f(4*P1);
  float2* ctall= (float2*)alloc_f(4*P1);
  float2* EWf  = (float2*)alloc_f(2*(size_t)WW*WW);
  float2* EWi  = (float2*)alloc_f(2*(size_t)WW*WW);
  float2* EHf  = (float2*)alloc_f(2*(size_t)HH*HH);
  float2* EHi  = (float2*)alloc_f(2*(size_t)HH*HH);

  const dim3 MG(6, 8, BB2);       // conv: 32x20 strips (5 pipelined 32x4 tiles), 768 blocks
  const dim3 LG(23, 20, BB2);     // l1 convs: 8x8 tiles
  const int NP1 = (int)((P1 + 255)/256);
  const int NP2 = (int)((2*P1 + 255)/256);
  const int DFTG = BB2*HH;        // 2560
  const int DFTB = 192;

  gen_dft2<<<(WW*WW+255)/256, 256, 0, stream>>>(EWf, EWi, WW);
  gen_dft2<<<(HH*HH+255)/256, 256, 0, stream>>>(EHf, EHi, HH);
  prep_all<<<12*36, 256, 0, stream>>>(cw, wp0);
  unpack_m<<<NP2, 256, 0, stream>>>(x1in, x2in, xall);

  // cterm = ifft2(mask*k), both branches
  maskk_m<<<NP2, 256, 0, stream>>>(k1, k2, mask, t1);
  dft_col_c<<<DFTG, DFTB, 0, stream>>>(t1, t2, EHi);
  dft_row_c<<<DFTG, DFTB, 0, stream>>>(t2, ctall, EWi);

  u16* WA[6]; u16* WB[6];
  for (int i = 0; i < 6; ++i) { WA[i] = wp0 + (size_t)i*18432; WB[i] = wp0 + (size_t)(6+i)*18432; }

  for (int ph = 0; ph < 3; ++ph) {
    // grad_r both branches
    l1fwd<<<LG, 256, 0, stream>>>(xall, cw.p[0], cw.p[1], cw.p[8], cw.p[9], act1);
    conv_mfma<1><<<MG, 256, 0, stream>>>(act1, WA[0], WB[0], act2, nullptr, nullptr, nullptr);
    conv_mfma<1><<<MG, 256, 0, stream>>>(act2, WA[1], WB[1], act3, nullptr, nullptr, nullptr);
    conv_mfma<3><<<MG, 256, 0, stream>>>(act3, WA[2], WB[2], w4b, nullptr, thr1, thr2);
    conv_mfma<2><<<MG, 256, 0, stream>>>(w4b,  WA[3], WB[3], act3, act3, nullptr, nullptr);
    conv_mfma<2><<<MG, 256, 0, stream>>>(act3, WA[4], WB[4], act2, act2, nullptr, nullptr);
    conv_mfma<2><<<MG, 256, 0, stream>>>(act2, WA[5], WB[5], act1, act1, nullptr, nullptr);
    l1bwd<<<LG, 256, 0, stream>>>(act1, cw.p[0], cw.p[1], cw.p[8], cw.p[9], grp);
    // grad_f both branches + fused update
    dft_row_planes<<<DFTG, DFTB, 0, stream>>>(xall, t1, EWf);
    dft_col_c<<<DFTG, DFTB, 0, stream>>>(t1, t2, EHf);
    dft_col_mask<<<DFTG, DFTB, 0, stream>>>(t2, t1, EHi, mask);
    dft_row_update<<<DFTG, DFTB, 0, stream>>>(t1, EWi, ctall, grp, xall,
                                              al1, al2, be1, be2, ph);
  }

  pack_kernel<<<NP1, 256, 0, stream>>>(xall, out);
}

// Round 8
// 3035.034 us; speedup vs baseline: 1.3279x; 1.3279x over previous
//
#include <hip/hip_runtime.h>
#include <math.h>

#define HH 160
#define WW 180
#define HWSZ (HH*WW)
#define BB 8
#define BB2 16                           // both branches merged in z
#define P1 ((size_t)BB*HWSZ)             // 230400 (one branch, one plane)
#define PE2 ((size_t)BB2*32*HWSZ)        // merged 32-ch plane set (both branches)

typedef unsigned short u16;
typedef unsigned long long ull;
typedef __attribute__((ext_vector_type(8))) short short8;
typedef __attribute__((ext_vector_type(2))) unsigned long long ull2;
typedef __attribute__((ext_vector_type(4))) float floatx4;

struct Ptrs16 { const float* p[16]; };

// ---------------- bf16 helpers ----------------
__device__ __forceinline__ u16 f2b(float f) {
  unsigned u = __builtin_bit_cast(unsigned, f);
  unsigned r = (u + 0x7fffu + ((u >> 16) & 1u)) >> 16;
  return (u16)r;
}
__device__ __forceinline__ float b2f(u16 h) {
  return __builtin_bit_cast(float, ((unsigned)h) << 16);
}

// ---------------- activation (eq. 33), delta = 0.01 ----------------
__device__ __forceinline__ float actf(float x) {
  float q = x*x*25.0f + 0.5f*x + 0.0025f;
  float r = fmaxf(x, 0.0f);
  return (fabsf(x) > 0.01f) ? r : q;
}
__device__ __forceinline__ float actdf(float x) {
  float q = x*50.0f + 0.5f;
  float r = (x > 0.0f) ? 1.0f : 0.0f;
  return (fabsf(x) > 0.01f) ? r : q;
}

// ---------------- weight prep, all 12 slots in one dispatch ----------------
// fp32 [o][c][9] -> bf16 [tap][nt][plane(r,i)][o16][c32], 18432 u16 per slot.
// -Wi is derived in-kernel by sign-bit XOR (R10-verified numerically exact).
__global__ void prep_all(Ptrs16 ps, u16* __restrict__ dst0) {
  const int rIdx[12] = {2,4,6,6,4,2,10,12,14,14,12,10};
  const int bwdF[12] = {0,0,0,1,1,1,0,0,0,1,1,1};
  int slot = blockIdx.x / 36;
  int idx = (blockIdx.x % 36)*256 + threadIdx.x;
  if (idx >= 9*32*32) return;
  const float* wr = ps.p[rIdx[slot]];
  const float* wi = ps.p[rIdx[slot]+1];
  u16* dst = dst0 + (size_t)slot*18432;
  int tap = idx >> 10; int rem = idx & 1023; int o = rem >> 5; int c = rem & 31;
  int s = bwdF[slot] ? ((c*32 + o)*9 + (8 - tap)) : ((o*32 + c)*9 + tap);
  float vr = wr[s], vi = wi[s];
  int nt = o >> 4, m = o & 15;
  size_t base = (((size_t)tap*2 + nt)*2*16 + (size_t)m)*32 + c;
  dst[base]       = f2b(vr);
  dst[base + 512] = f2b(vi);
}

// ---------------- MFMA complex conv 32->32, 3x3 SAME, implicit GEMM (R3-proven) ----
// NHWC bf16: addr = ((b*HH+y)*WW+x)*32 + ch, R at 0, I at +PE2. b in [0,16): branch=b>>3.
// Tile 32x4, 4 waves (wave=row), 2 m-segments, 256 threads. LDS 26112 B (6 blk/CU).
// T2 XOR swizzle byteaddr ^= ((B>>7)&7)<<4 at write AND read (R3-verified).
// OPERAND-SWAPPED MFMA: A=weights (M=och), B=pixels (N=px) -> D row=och, col=px.
// MODE: 1 act, 2 cmul by actdf(der)
template<int MODE>
__global__ __launch_bounds__(256, 6)
void conv_mfma(const u16* __restrict__ inb, const u16* __restrict__ wbA,
               const u16* __restrict__ wbB, u16* __restrict__ outb,
               const u16* __restrict__ derb,
               const float* __restrict__ thrA, const float* __restrict__ thrB)
{
  __shared__ alignas(128) u16 stg[2*6*34*32];   // 26112 B
  const int tid = threadIdx.x;
  const int lane = tid & 63, wv = tid >> 6;
  const int x0 = blockIdx.x * 32, y0 = blockIdx.y * 4, b = blockIdx.z;
  const u16* wb = (b < BB) ? wbA : wbB;
  const int m = lane & 15, q = lane >> 4;

  for (int j = tid; j < 1632; j += 256) {
    int prow = j / 136; int rem = j - prow*136;
    int col = rem >> 2, chq = rem & 3;
    int plane = prow / 6, row = prow - plane*6;
    int gy = y0 - 1 + row, gx = x0 - 1 + col;
    ull v0 = 0, v1 = 0;
    if (gy >= 0 && gy < HH && gx >= 0 && gx < WW) {
      const ull* src = (const ull*)(inb + (size_t)plane*PE2
                                    + (((size_t)b*HH + gy)*WW + gx)*32 + chq*8);
      v0 = src[0]; v1 = src[1];
    }
    int B = prow*2176 + col*64 + chq*16;
    B ^= ((B >> 7) & 7) << 4;
    ull* dst = (ull*)((char*)stg + B);
    dst[0] = v0; dst[1] = v1;
  }
  __syncthreads();

  floatx4 accr[2][2], acci[2][2];   // [seg][nt]
#pragma unroll
  for (int s = 0; s < 2; ++s)
#pragma unroll
    for (int nt = 0; nt < 2; ++nt) {
      accr[s][nt] = (floatx4){0.f,0.f,0.f,0.f};
      acci[s][nt] = (floatx4){0.f,0.f,0.f,0.f};
    }

#pragma unroll
  for (int tap = 0; tap < 9; ++tap) {
    const int ky = tap / 3, kx = tap - ky*3;
    short8 Pr[2], Pi[2];
#pragma unroll
    for (int s = 0; s < 2; ++s) {
      int col = s*16 + m + kx;
      int BR = ((wv + ky)*34 + col)*64 + q*16;
      int BI = BR + 13056;
      BR ^= ((BR >> 7) & 7) << 4;
      BI ^= ((BI >> 7) & 7) << 4;
      const ull* pR = (const ull*)((const char*)stg + BR);
      const ull* pI = (const ull*)((const char*)stg + BI);
      ull2 vr; vr.x = pR[0]; vr.y = pR[1];
      ull2 vi; vi.x = pI[0]; vi.y = pI[1];
      Pr[s] = __builtin_bit_cast(short8, vr);
      Pi[s] = __builtin_bit_cast(short8, vi);
    }
#pragma unroll
    for (int nt = 0; nt < 2; ++nt) {
      const u16* pw = wb + (size_t)(tap*2 + nt)*1024 + (size_t)m*32 + q*8;
      short8 Wr = *(const short8*)pw;
      short8 Wi = *(const short8*)(pw + 512);
      ull2 wx = __builtin_bit_cast(ull2, Wi);
      wx.x ^= 0x8000800080008000ULL;
      wx.y ^= 0x8000800080008000ULL;
      short8 nWi = __builtin_bit_cast(short8, wx);
#pragma unroll
      for (int s = 0; s < 2; ++s) {
        accr[s][nt] = __builtin_amdgcn_mfma_f32_16x16x32_bf16(Wr,  Pr[s], accr[s][nt], 0, 0, 0);
        accr[s][nt] = __builtin_amdgcn_mfma_f32_16x16x32_bf16(nWi, Pi[s], accr[s][nt], 0, 0, 0);
        acci[s][nt] = __builtin_amdgcn_mfma_f32_16x16x32_bf16(Wr,  Pi[s], acci[s][nt], 0, 0, 0);
        acci[s][nt] = __builtin_amdgcn_mfma_f32_16x16x32_bf16(Wi,  Pr[s], acci[s][nt], 0, 0, 0);
      }
    }
  }

  const int y = y0 + wv;
#pragma unroll
  for (int s = 0; s < 2; ++s) {
    int x = x0 + s*16 + m;
    bool ok = (x < WW);
    size_t pxbase = (((size_t)b*HH + y)*WW + x)*32;
#pragma unroll
    for (int nt = 0; nt < 2; ++nt) {
      size_t gb = pxbase + nt*16 + q*4;
      ull dR = 0, dI = 0;
      if constexpr (MODE == 2) {
        if (ok) { dR = *(const ull*)(derb + gb); dI = *(const ull*)(derb + PE2 + gb); }
      }
      ull vR = 0, vI = 0;
#pragma unroll
      for (int r = 0; r < 4; ++r) {
        float pr = accr[s][nt][r], pi = acci[s][nt][r];
        if constexpr (MODE == 1) { pr = actf(pr); pi = actf(pi); }
        if constexpr (MODE == 2) {
          float dr = actdf(b2f((u16)(dR >> (16*r))));
          float di = actdf(b2f((u16)(dI >> (16*r))));
          float nr = pr*dr - pi*di;
          pi = pr*di + pi*dr; pr = nr;
        }
        vR |= (ull)f2b(pr) << (16*r);
        vI |= (ull)f2b(pi) << (16*r);
      }
      if (ok) {
        *(ull*)(outb + gb)       = vR;
        *(ull*)(outb + PE2 + gb) = vI;
      }
    }
  }
  (void)thrA; (void)thrB;
}

// ---------------- FUSED: conv4-fwd + channel-norm + conv4T-bwd + actdf cmul ----------
// Replaces the mode3+mode2 pair at layer 4. Input act3; output w4b buffer. The
// derivative source == input (act3), already staged -> zero extra traffic; the w4b
// global round-trip (write + halo re-read) is eliminated.
// Tile 32x4 output. Stage input rows y0-2..y0+5 x cols x0-2..x0+33 (8x36, 2 planes)
// into LDS layout A (36864 B). Compute intermediate = normalize(conv4(input)) at the
// 6x34 halo grid (204 px, 13 groups of 16, distributed 3/3/3/4 over 4 waves), held in
// regs as packed bf16; after a barrier the SAME LDS is rewritten as layout B
// [plane][6][34][ch32] (26112 B); bwd = verified mode-2 loop on layout B with slot-3
// weights, cmul with actdf of input values extracted to regs before the overwrite.
// R7 BUGFIX: intermediate points whose (gy,gx) lie OUTSIDE the image must be ZERO
// (the unfused pipeline never stored them; its bwd staging zero-padded). A boundary
// intermediate's stencil touches in-image inputs, so conv!=0 there -> force invn=0.
// XOR swizzle ^((B>>7)&7)<<4 on every LDS byte address (A and B; sizes mult. of 128).
__global__ __launch_bounds__(256, 3)
void conv_f34(const u16* __restrict__ inb,
              const u16* __restrict__ wfA, const u16* __restrict__ wfB,
              const u16* __restrict__ wbA, const u16* __restrict__ wbB,
              u16* __restrict__ outb,
              const float* __restrict__ thrA, const float* __restrict__ thrB)
{
  __shared__ alignas(128) u16 stg[18432];        // 36864 B
  const int tid = threadIdx.x;
  const int lane = tid & 63, wv = tid >> 6;
  const int x0 = blockIdx.x*32, y0 = blockIdx.y*4, b = blockIdx.z;
  const u16* wf = (b < BB) ? wfA : wfB;
  const u16* wbk = (b < BB) ? wbA : wbB;
  const float thr = (b < BB ? thrA : thrB)[0];
  const int m = lane & 15, q = lane >> 4;

  // ---- stage input region: 2304 16B chunks (plane8row x col36 x chq4) ----
  for (int j = tid; j < 2304; j += 256) {
    int prow = j / 144; int rem = j - prow*144;
    int col = rem >> 2, chq = rem & 3;
    int plane = prow >> 3, row = prow & 7;
    int gy = y0 - 2 + row, gx = x0 - 2 + col;
    ull v0 = 0, v1 = 0;
    if (gy >= 0 && gy < HH && gx >= 0 && gx < WW) {
      const ull* src = (const ull*)(inb + (size_t)plane*PE2
                                    + (((size_t)b*HH + gy)*WW + gx)*32 + chq*8);
      v0 = src[0]; v1 = src[1];
    }
    int B = (prow*36 + col)*64 + chq*16;
    B ^= ((B >> 7) & 7) << 4;
    ull* dst = (ull*)((char*)stg + B);
    dst[0] = v0; dst[1] = v1;
  }
  __syncthreads();

  // ---- extract actdf inputs (center px, own och chunk) before LDS overwrite ----
  ull exR[2][2], exI[2][2];   // [s][nt]: 4 och bf16 each
#pragma unroll
  for (int s = 0; s < 2; ++s)
#pragma unroll
    for (int nt = 0; nt < 2; ++nt) {
      int BA = ((2 + wv)*36 + (2 + s*16 + m))*64 + nt*32 + q*8;
      int BI = BA + 18432;
      BA ^= ((BA >> 7) & 7) << 4;
      BI ^= ((BI >> 7) & 7) << 4;
      exR[s][nt] = *(const ull*)((const char*)stg + BA);
      exI[s][nt] = *(const ull*)((const char*)stg + BI);
    }

  // ---- forward conv4 + normalize at 6x34 intermediate grid ----
  const int ng = (wv == 3) ? 4 : 3;
  ull pRk[4][2], pIk[4][2];   // packed normalized bf16 [gi][nt]
#pragma unroll
  for (int gi = 0; gi < 4; ++gi) {
    if (gi < ng) {
      int g = wv*3 + gi;
      int p = g*16 + m;
      bool pv = (p < 204);
      int irow = pv ? (p / 34) : 0;
      int icol = pv ? (p - irow*34) : 0;
      floatx4 fr[2], fi[2];
#pragma unroll
      for (int nt = 0; nt < 2; ++nt) {
        fr[nt] = (floatx4){0.f,0.f,0.f,0.f};
        fi[nt] = (floatx4){0.f,0.f,0.f,0.f};
      }
#pragma unroll
      for (int tap = 0; tap < 9; ++tap) {
        int ky = tap/3, kx = tap - ky*3;
        int BA = ((irow + ky)*36 + (icol + kx))*64 + q*16;
        int BI = BA + 18432;
        BA ^= ((BA >> 7) & 7) << 4;
        BI ^= ((BI >> 7) & 7) << 4;
        const ull* pR = (const ull*)((const char*)stg + BA);
        const ull* pI = (const ull*)((const char*)stg + BI);
        ull2 vr; vr.x = pR[0]; vr.y = pR[1];
        ull2 vi; vi.x = pI[0]; vi.y = pI[1];
        short8 Pr = __builtin_bit_cast(short8, vr);
        short8 Pi = __builtin_bit_cast(short8, vi);
#pragma unroll
        for (int nt = 0; nt < 2; ++nt) {
          const u16* pw = wf + (size_t)(tap*2 + nt)*1024 + (size_t)m*32 + q*8;
          short8 Wr = *(const short8*)pw;
          short8 Wi = *(const short8*)(pw + 512);
          ull2 wx = __builtin_bit_cast(ull2, Wi);
          wx.x ^= 0x8000800080008000ULL;
          wx.y ^= 0x8000800080008000ULL;
          short8 nWi = __builtin_bit_cast(short8, wx);
          fr[nt] = __builtin_amdgcn_mfma_f32_16x16x32_bf16(Wr,  Pr, fr[nt], 0, 0, 0);
          fr[nt] = __builtin_amdgcn_mfma_f32_16x16x32_bf16(nWi, Pi, fr[nt], 0, 0, 0);
          fi[nt] = __builtin_amdgcn_mfma_f32_16x16x32_bf16(Wr,  Pi, fi[nt], 0, 0, 0);
          fi[nt] = __builtin_amdgcn_mfma_f32_16x16x32_bf16(Wi,  Pr, fi[nt], 0, 0, 0);
        }
      }
      // per-px 32-och norm (sum over nt,r in-lane; over q via shfl 16,32 —
      // lanes {m, m+16, m+32, m+48} all hold the SAME pixel p, different och chunks)
      float ss = 0.f;
#pragma unroll
      for (int nt = 0; nt < 2; ++nt)
#pragma unroll
        for (int r = 0; r < 4; ++r)
          ss += fr[nt][r]*fr[nt][r] + fi[nt][r]*fi[nt][r];
      ss += __shfl_xor(ss, 16, 64);
      ss += __shfl_xor(ss, 32, 64);
      float invn = 1.0f / fmaxf(sqrtf(ss), thr);
      // R7 FIX: out-of-image intermediate must be exactly 0
      int gyi = y0 - 1 + irow, gxi = x0 - 1 + icol;
      if (gyi < 0 || gyi >= HH || gxi < 0 || gxi >= WW) invn = 0.0f;
#pragma unroll
      for (int nt = 0; nt < 2; ++nt) {
        ull vR = 0, vI = 0;
#pragma unroll
        for (int r = 0; r < 4; ++r) {
          vR |= (ull)f2b(fr[nt][r]*invn) << (16*r);
          vI |= (ull)f2b(fi[nt][r]*invn) << (16*r);
        }
        pRk[gi][nt] = vR; pIk[gi][nt] = vI;
      }
    }
  }
  __syncthreads();   // all layout-A reads complete

  // ---- write normalized intermediate, layout B [plane][6][34][ch32] ----
#pragma unroll
  for (int gi = 0; gi < 4; ++gi) {
    if (gi < ng) {
      int g = wv*3 + gi;
      int p = g*16 + m;
      if (p < 204) {
        int irow = p / 34, icol = p - irow*34;
        int base = (irow*34 + icol)*64;
#pragma unroll
        for (int nt = 0; nt < 2; ++nt) {
          int BA = base + nt*32 + q*8;
          int BI = BA + 13056;
          BA ^= ((BA >> 7) & 7) << 4;
          BI ^= ((BI >> 7) & 7) << 4;
          *(ull*)((char*)stg + BA) = pRk[gi][nt];
          *(ull*)((char*)stg + BI) = pIk[gi][nt];
        }
      }
    }
  }
  __syncthreads();

  // ---- backward convT4 on layout B, slot-3 weights ----
  floatx4 accr[2][2], acci[2][2];
#pragma unroll
  for (int s = 0; s < 2; ++s)
#pragma unroll
    for (int nt = 0; nt < 2; ++nt) {
      accr[s][nt] = (floatx4){0.f,0.f,0.f,0.f};
      acci[s][nt] = (floatx4){0.f,0.f,0.f,0.f};
    }

#pragma unroll
  for (int tap = 0; tap < 9; ++tap) {
    const int ky = tap / 3, kx = tap - ky*3;
    short8 Pr[2], Pi[2];
#pragma unroll
    for (int s = 0; s < 2; ++s) {
      int col = s*16 + m + kx;
      int BR = ((wv + ky)*34 + col)*64 + q*16;
      int BI = BR + 13056;
      BR ^= ((BR >> 7) & 7) << 4;
      BI ^= ((BI >> 7) & 7) << 4;
      const ull* pR = (const ull*)((const char*)stg + BR);
      const ull* pI = (const ull*)((const char*)stg + BI);
      ull2 vr; vr.x = pR[0]; vr.y = pR[1];
      ull2 vi; vi.x = pI[0]; vi.y = pI[1];
      Pr[s] = __builtin_bit_cast(short8, vr);
      Pi[s] = __builtin_bit_cast(short8, vi);
    }
#pragma unroll
    for (int nt = 0; nt < 2; ++nt) {
      const u16* pw = wbk + (size_t)(tap*2 + nt)*1024 + (size_t)m*32 + q*8;
      short8 Wr = *(const short8*)pw;
      short8 Wi = *(const short8*)(pw + 512);
      ull2 wx = __builtin_bit_cast(ull2, Wi);
      wx.x ^= 0x8000800080008000ULL;
      wx.y ^= 0x8000800080008000ULL;
      short8 nWi = __builtin_bit_cast(short8, wx);
#pragma unroll
      for (int s = 0; s < 2; ++s) {
        accr[s][nt] = __builtin_amdgcn_mfma_f32_16x16x32_bf16(Wr,  Pr[s], accr[s][nt], 0, 0, 0);
        accr[s][nt] = __builtin_amdgcn_mfma_f32_16x16x32_bf16(nWi, Pi[s], accr[s][nt], 0, 0, 0);
        acci[s][nt] = __builtin_amdgcn_mfma_f32_16x16x32_bf16(Wr,  Pi[s], acci[s][nt], 0, 0, 0);
        acci[s][nt] = __builtin_amdgcn_mfma_f32_16x16x32_bf16(Wi,  Pr[s], acci[s][nt], 0, 0, 0);
      }
    }
  }

  // ---- epilogue: cmul by actdf(extracted input), store to outb ----
  const int y = y0 + wv;
#pragma unroll
  for (int s = 0; s < 2; ++s) {
    int x = x0 + s*16 + m;
    bool ok = (x < WW);
    size_t pxbase = (((size_t)b*HH + y)*WW + x)*32;
#pragma unroll
    for (int nt = 0; nt < 2; ++nt) {
      size_t gb = pxbase + nt*16 + q*4;
      ull dR = exR[s][nt], dI = exI[s][nt];
      ull vR = 0, vI = 0;
#pragma unroll
      for (int r = 0; r < 4; ++r) {
        float pr = accr[s][nt][r], pi = acci[s][nt][r];
        float dr = actdf(b2f((u16)(dR >> (16*r))));
        float di = actdf(b2f((u16)(dI >> (16*r))));
        float nr = pr*dr - pi*di;
        pi = pr*di + pi*dr; pr = nr;
        vR |= (ull)f2b(pr) << (16*r);
        vI |= (ull)f2b(pi) << (16*r);
      }
      if (ok) {
        *(ull*)(outb + gb)       = vR;
        *(ull*)(outb + PE2 + gb) = vI;
      }
    }
  }
}

// ---------------- layer-1 forward: complex conv 1->32 + act, planar fp32 -> NHWC bf16
__global__ __launch_bounds__(256)
void l1fwd(const float* __restrict__ xall,
           const float* __restrict__ wrA, const float* __restrict__ wiA,
           const float* __restrict__ wrB, const float* __restrict__ wiB,
           u16* __restrict__ outb)
{
  __shared__ float hR[10][12], hI[10][12];
  __shared__ float wt[9][32][2];
  const int tid = threadIdx.x;
  const int og = tid & 3, px = tid >> 2;
  const int lx = px & 7, ly = px >> 3;
  const int x0 = blockIdx.x*8, y0 = blockIdx.y*8, b = blockIdx.z;
  const int branch = b >> 3, img = b & 7;
  const float* wr = branch ? wrB : wrA;
  const float* wi = branch ? wiB : wiA;
  const float* xp = xall + (size_t)branch*2*P1 + (size_t)img*HWSZ;

  for (int j = tid; j < 576; j += 256) {
    int tap = j >> 6; int rem = j & 63; int o = rem >> 1, ri = rem & 1;
    wt[tap][o][ri] = ri ? wi[o*9+tap] : wr[o*9+tap];
  }
  for (int j = tid; j < 200; j += 256) {
    int plane = j / 100; int pos = j - plane*100;
    int yy = pos / 10, xx = pos - yy*10;
    int gy = y0 - 1 + yy, gx = x0 - 1 + xx;
    float v = 0.f;
    if (gy >= 0 && gy < HH && gx >= 0 && gx < WW)
      v = xp[(size_t)plane*P1 + (size_t)gy*WW + gx];
    (plane ? hI : hR)[yy][xx] = v;
  }
  __syncthreads();

  float accR[8], accI[8];
#pragma unroll
  for (int o = 0; o < 8; ++o) { accR[o] = 0.f; accI[o] = 0.f; }
#pragma unroll
  for (int tap = 0; tap < 9; ++tap) {
    int ky = tap/3, kx = tap - ky*3;
    float ar = hR[ly+ky][lx+kx], ai = hI[ly+ky][lx+kx];
#pragma unroll
    for (int o = 0; o < 8; ++o) {
      float wrv = wt[tap][og*8+o][0], wiv = wt[tap][og*8+o][1];
      accR[o] += ar*wrv - ai*wiv;
      accI[o] += ar*wiv + ai*wrv;
    }
  }
  int gx = x0 + lx, gy = y0 + ly;
  if (gx < WW) {
    size_t base = (((size_t)b*HH + gy)*WW + gx)*32 + og*8;
    ull* dR = (ull*)(outb + base);
    ull* dI = (ull*)(outb + PE2 + base);
#pragma unroll
    for (int k = 0; k < 2; ++k) {
      ull vR = 0, vI = 0;
#pragma unroll
      for (int t = 0; t < 4; ++t) {
        vR |= (ull)f2b(actf(accR[k*4+t])) << (16*t);
        vI |= (ull)f2b(actf(accI[k*4+t])) << (16*t);
      }
      dR[k] = vR; dI[k] = vI;
    }
  }
}

// ---------------- layer-1 backward: complex convT 32->1, NHWC bf16 -> planar fp32 ----
__global__ __launch_bounds__(256)
void l1bwd(const u16* __restrict__ gb,
           const float* __restrict__ wrA, const float* __restrict__ wiA,
           const float* __restrict__ wrB, const float* __restrict__ wiB,
           float* __restrict__ outp)
{
  __shared__ alignas(16) u16 stg[2*100*32];   // [plane][pos10x10][ch32] = 12.5 KB
  __shared__ float wt[32][9][2];
  const int tid = threadIdx.x;
  const int cg = tid & 3, px = tid >> 2;
  const int lx = px & 7, ly = px >> 3;
  const int x0 = blockIdx.x*8, y0 = blockIdx.y*8, b = blockIdx.z;
  const int branch = b >> 3, img = b & 7;
  const float* wr = branch ? wrB : wrA;
  const float* wi = branch ? wiB : wiA;

  for (int j = tid; j < 576; j += 256) {
    int c = j / 18; int rem = j - c*18; int tap = rem >> 1, ri = rem & 1;
    wt[c][tap][ri] = (ri ? wi : wr)[c*9 + (8-tap)];
  }
  for (int j = tid; j < 800; j += 256) {
    int plane = j / 400; int rem = j - plane*400;
    int pos = rem >> 2, chq = rem & 3;
    int yy = pos / 10, xx = pos - yy*10;
    int gy = y0 - 1 + yy, gx = x0 - 1 + xx;
    ull v0 = 0, v1 = 0;
    if (gy >= 0 && gy < HH && gx >= 0 && gx < WW) {
      const ull* src = (const ull*)(gb + (size_t)plane*PE2
                                    + (((size_t)b*HH + gy)*WW + gx)*32 + chq*8);
      v0 = src[0]; v1 = src[1];
    }
    ull* dst = (ull*)&stg[((size_t)plane*100 + pos)*32 + chq*8];
    dst[0] = v0; dst[1] = v1;
  }
  __syncthreads();

  float gr = 0.f, gi = 0.f;
#pragma unroll
  for (int tap = 0; tap < 9; ++tap) {
    int ky = tap/3, kx = tap - ky*3;
    int pos = (ly+ky)*10 + (lx+kx);
    const ull* pR = (const ull*)&stg[(size_t)pos*32 + cg*8];
    const ull* pI = (const ull*)&stg[(100 + (size_t)pos)*32 + cg*8];
    ull r0 = pR[0], r1 = pR[1], i0 = pI[0], i1 = pI[1];
#pragma unroll
    for (int t = 0; t < 4; ++t) {
      int c = cg*8 + t;
      float ar = b2f((u16)(r0 >> (16*t))), ai = b2f((u16)(i0 >> (16*t)));
      float wrv = wt[c][tap][0], wiv = wt[c][tap][1];
      gr += ar*wrv - ai*wiv;
      gi += ar*wiv + ai*wrv;
    }
#pragma unroll
    for (int t = 0; t < 4; ++t) {
      int c = cg*8 + 4 + t;
      float ar = b2f((u16)(r1 >> (16*t))), ai = b2f((u16)(i1 >> (16*t)));
      float wrv = wt[c][tap][0], wiv = wt[c][tap][1];
      gr += ar*wrv - ai*wiv;
      gi += ar*wiv + ai*wrv;
    }
  }
  gr += __shfl_xor(gr, 1, 64); gr += __shfl_xor(gr, 2, 64);
  gi += __shfl_xor(gi, 1, 64); gi += __shfl_xor(gi, 2, 64);

  int gx = x0 + lx, gy = y0 + ly;
  if (cg == 0 && gx < WW) {
    size_t o2 = (size_t)branch*2*P1 + (size_t)img*HWSZ + (size_t)gy*WW + gx;
    outp[o2]      = gr;
    outp[P1 + o2] = gi;
  }
}

// ---------------- DFT machinery ----------------
__global__ void gen_dft2(float2* __restrict__ Mf, float2* __restrict__ Mi, int N) {
  int idx = blockIdx.x*256 + threadIdx.x;
  if (idx >= N*N) return;
  int r = idx / N, c = idx - r*N;
  long mm = ((long)r * (long)c) % N;
  double a = 2.0 * 3.14159265358979323846 * (double)mm / (double)N;
  double cs = cos(a), sn = sin(a);
  Mf[idx] = make_float2((float)cs, (float)(-sn));
  Mi[idx] = make_float2((float)(cs/N), (float)(sn/N));
}

__global__ void dft_row_planes(const float* __restrict__ xall,
                               float2* __restrict__ out, const float2* __restrict__ M) {
  int bh = blockIdx.x;
  int v = threadIdx.x; if (v >= WW) return;
  int b2 = bh / HH, h = bh - b2*HH;
  int branch = b2 >> 3, img = b2 & 7;
  const float* rowR = xall + (size_t)branch*2*P1 + (size_t)img*HWSZ + (size_t)h*WW;
  const float* rowI = rowR + P1;
  float ar = 0.f, ai = 0.f;
  for (int w = 0; w < WW; ++w) {
    float sr = rowR[w], si = rowI[w];
    float2 m = M[w*WW + v];
    ar += sr*m.x - si*m.y;
    ai += sr*m.y + si*m.x;
  }
  out[(size_t)bh*WW + v] = make_float2(ar, ai);
}

__global__ void dft_row_c(const float2* __restrict__ in, float2* __restrict__ out,
                          const float2* __restrict__ M) {
  int bh = blockIdx.x;
  int v = threadIdx.x; if (v >= WW) return;
  const float2* row = in + (size_t)bh*WW;
  float ar = 0.f, ai = 0.f;
  for (int w = 0; w < WW; ++w) {
    float2 s = row[w];
    float2 m = M[w*WW + v];
    ar += s.x*m.x - s.y*m.y;
    ai += s.x*m.y + s.y*m.x;
  }
  out[(size_t)bh*WW + v] = make_float2(ar, ai);
}

__global__ void dft_col_c(const float2* __restrict__ in, float2* __restrict__ out,
                          const float2* __restrict__ M) {
  int bu = blockIdx.x;
  int v = threadIdx.x; if (v >= WW) return;
  int b = bu / HH, u = bu - b*HH;
  const float2* base = in + (size_t)b*HWSZ;
  float ar = 0.f, ai = 0.f;
  for (int h = 0; h < HH; ++h) {
    float2 m = M[u*HH + h];
    float2 s = base[(size_t)h*WW + v];
    ar += s.x*m.x - s.y*m.y;
    ai += s.x*m.y + s.y*m.x;
  }
  out[(size_t)bu*WW + v] = make_float2(ar, ai);
}

__global__ void dft_col_mask(const float2* __restrict__ in, float2* __restrict__ out,
                             const float2* __restrict__ M, const float* __restrict__ mask) {
  int bu = blockIdx.x;
  int v = threadIdx.x; if (v >= WW) return;
  int b = bu / HH, u = bu - b*HH;
  const float2* base = in + (size_t)b*HWSZ;
  float ar = 0.f, ai = 0.f;
  for (int h = 0; h < HH; ++h) {
    float mk = mask[h*WW + v]; float mm = mk*mk;
    float2 m = M[u*HH + h];
    float2 s = base[(size_t)h*WW + v];
    float sr = s.x*mm, si = s.y*mm;
    ar += sr*m.x - si*m.y;
    ai += sr*m.y + si*m.x;
  }
  out[(size_t)bu*WW + v] = make_float2(ar, ai);
}

__global__ void dft_row_update(const float2* __restrict__ in, const float2* __restrict__ M,
                               const float2* __restrict__ ctall, const float* __restrict__ grp,
                               float* __restrict__ xall,
                               const float* __restrict__ al1, const float* __restrict__ al2,
                               const float* __restrict__ be1, const float* __restrict__ be2,
                               int phase) {
  int bh = blockIdx.x;
  int v = threadIdx.x; if (v >= WW) return;
  int b2 = bh / HH, h = bh - b2*HH;
  int branch = b2 >> 3, img = b2 & 7;
  const float2* row = in + (size_t)bh*WW;
  float ar = 0.f, ai = 0.f;
  for (int w = 0; w < WW; ++w) {
    float2 s = row[w];
    float2 m = M[w*WW + v];
    ar += s.x*m.x - s.y*m.y;
    ai += s.x*m.y + s.y*m.x;
  }
  float2 ct = ctall[(size_t)bh*WW + v];
  float a   = (branch ? al2 : al1)[phase];
  float bet = (branch ? be2 : be1)[phase];
  size_t xo = (size_t)branch*2*P1 + (size_t)img*HWSZ + (size_t)h*WW + v;
  xall[xo]      -= a*(ar - ct.x) + bet*grp[xo];
  xall[P1 + xo] -= a*(ai - ct.y) + bet*grp[P1 + xo];
}

// ---------------- small pointwise kernels ----------------
__global__ void maskk_m(const float* __restrict__ k1, const float* __restrict__ k2,
                        const float* __restrict__ mask, float2* __restrict__ t) {
  int i = blockIdx.x*256 + threadIdx.x;
  if (i >= (int)(2*P1)) return;
  int branch = i >= (int)P1;
  int ii = i - branch*(int)P1;
  int b = ii / HWSZ, p = ii - b*HWSZ;
  const float* k = branch ? k2 : k1;
  float m = mask[p];
  t[i] = make_float2(m * k[(size_t)b*2*HWSZ + p], m * k[(size_t)b*2*HWSZ + HWSZ + p]);
}

__global__ void unpack_m(const float* __restrict__ x1, const float* __restrict__ x2,
                         float* __restrict__ xall) {
  int i = blockIdx.x*256 + threadIdx.x;
  if (i >= (int)(2*P1)) return;
  int branch = i >= (int)P1;
  int ii = i - branch*(int)P1;
  int b = ii / HWSZ, p = ii - b*HWSZ;
  const float* src = branch ? x2 : x1;
  size_t dst = (size_t)branch*2*P1 + (size_t)b*HWSZ + p;
  xall[dst]      = src[(size_t)b*2*HWSZ + p];
  xall[P1 + dst] = src[(size_t)b*2*HWSZ + HWSZ + p];
}

__global__ void pack_kernel(const float* __restrict__ xall, float* __restrict__ out) {
  int i = blockIdx.x*256 + threadIdx.x;
  if (i >= (int)P1) return;
  int b = i / HWSZ, p = i - b*HWSZ;
  size_t ob = (size_t)b*4*HWSZ;
  size_t x1o = (size_t)b*HWSZ + p;
  size_t x2o = 2*P1 + x1o;
  out[ob + p]          = xall[x1o];
  out[ob + HWSZ + p]   = xall[P1 + x1o];
  out[ob + 2*HWSZ + p] = xall[x2o];
  out[ob + 3*HWSZ + p] = xall[P1 + x2o];
}

// ---------------- launch ----------------
extern "C" void kernel_launch(void* const* d_in, const int* in_sizes, int n_in,
                              void* d_out, int out_size, void* d_ws, size_t ws_size,
                              hipStream_t stream) {
  (void)in_sizes; (void)n_in; (void)out_size; (void)ws_size;
  const float* x1in = (const float*)d_in[0];
  const float* x2in = (const float*)d_in[1];
  const float* k1   = (const float*)d_in[2];
  const float* k2   = (const float*)d_in[3];
  const float* mask = (const float*)d_in[4];
  Ptrs16 cw;
  for (int i = 0; i < 16; ++i) cw.p[i] = (const float*)d_in[5+i];
  const float* thr1 = (const float*)d_in[21];
  const float* thr2 = (const float*)d_in[22];
  const float* al1  = (const float*)d_in[23];
  const float* al2  = (const float*)d_in[24];
  const float* be1  = (const float*)d_in[25];
  const float* be2  = (const float*)d_in[26];
  float* out = (float*)d_out;

  // ---- workspace: bf16 region then fp32 region ----
  u16* U = (u16*)d_ws;
  size_t uoff = 0;
  auto alloc_u = [&](size_t n){ u16* p = U + uoff; uoff += (n + 15) & ~(size_t)15; return p; };
  u16* act1 = alloc_u(2*PE2);
  u16* act2 = alloc_u(2*PE2);
  u16* act3 = alloc_u(2*PE2);
  u16* w4b  = alloc_u(2*PE2);
  u16* wp0  = alloc_u(12*18432);

  float* F = (float*)(U + uoff);
  size_t off = 0;
  auto alloc_f = [&](size_t n){ float* p = F + off; off += (n + 3) & ~(size_t)3; return p; };
  float*  xall = alloc_f(4*P1);                       // [branch][plane][P1]
  float*  grp  = alloc_f(4*P1);
  float2* t1   = (float2*)alloc_f(4*P1);              // [16][HWSZ] complex
  float2* t2   = (float2*)alloc_f(4*P1);
  float2* ctall= (float2*)alloc_f(4*P1);
  float2* EWf  = (float2*)alloc_f(2*(size_t)WW*WW);
  float2* EWi  = (float2*)alloc_f(2*(size_t)WW*WW);
  float2* EHf  = (float2*)alloc_f(2*(size_t)HH*HH);
  float2* EHi  = (float2*)alloc_f(2*(size_t)HH*HH);

  const dim3 MG(6, 40, BB2);      // conv: 32x4 tiles (3840 blocks)
  const dim3 LG(23, 20, BB2);     // l1 convs: 8x8 tiles
  const int NP1 = (int)((P1 + 255)/256);
  const int NP2 = (int)((2*P1 + 255)/256);
  const int DFTG = BB2*HH;        // 2560
  const int DFTB = 192;

  gen_dft2<<<(WW*WW+255)/256, 256, 0, stream>>>(EWf, EWi, WW);
  gen_dft2<<<(HH*HH+255)/256, 256, 0, stream>>>(EHf, EHi, HH);
  prep_all<<<12*36, 256, 0, stream>>>(cw, wp0);
  unpack_m<<<NP2, 256, 0, stream>>>(x1in, x2in, xall);

  // cterm = ifft2(mask*k), both branches
  maskk_m<<<NP2, 256, 0, stream>>>(k1, k2, mask, t1);
  dft_col_c<<<DFTG, DFTB, 0, stream>>>(t1, t2, EHi);
  dft_row_c<<<DFTG, DFTB, 0, stream>>>(t2, ctall, EWi);

  u16* WA[6]; u16* WB[6];
  for (int i = 0; i < 6; ++i) { WA[i] = wp0 + (size_t)i*18432; WB[i] = wp0 + (size_t)(6+i)*18432; }

  for (int ph = 0; ph < 3; ++ph) {
    // grad_r both branches
    l1fwd<<<LG, 256, 0, stream>>>(xall, cw.p[0], cw.p[1], cw.p[8], cw.p[9], act1);
    conv_mfma<1><<<MG, 256, 0, stream>>>(act1, WA[0], WB[0], act2, nullptr, nullptr, nullptr);
    conv_mfma<1><<<MG, 256, 0, stream>>>(act2, WA[1], WB[1], act3, nullptr, nullptr, nullptr);
    conv_f34<<<MG, 256, 0, stream>>>(act3, WA[2], WB[2], WA[3], WB[3], w4b, thr1, thr2);
    conv_mfma<2><<<MG, 256, 0, stream>>>(w4b,  WA[4], WB[4], act2, act2, nullptr, nullptr);
    conv_mfma<2><<<MG, 256, 0, stream>>>(act2, WA[5], WB[5], act1, act1, nullptr, nullptr);
    l1bwd<<<LG, 256, 0, stream>>>(act1, cw.p[0], cw.p[1], cw.p[8], cw.p[9], grp);
    // grad_f both branches + fused update
    dft_row_planes<<<DFTG, DFTB, 0, stream>>>(xall, t1, EWf);
    dft_col_c<<<DFTG, DFTB, 0, stream>>>(t1, t2, EHf);
    dft_col_mask<<<DFTG, DFTB, 0, stream>>>(t2, t1, EHi, mask);
    dft_row_update<<<DFTG, DFTB, 0, stream>>>(t1, EWi, ctall, grp, xall,
                                              al1, al2, be1, be2, ph);
  }

  pack_kernel<<<NP1, 256, 0, stream>>>(xall, out);
}

// Round 9
// 2063.730 us; speedup vs baseline: 1.9529x; 1.4707x over previous
//
#include <hip/hip_runtime.h>
#include <math.h>

#define HH 160
#define WW 180
#define HWSZ (HH*WW)
#define BB 8
#define BB2 16                           // both branches merged in z
#define P1 ((size_t)BB*HWSZ)             // 230400 (one branch, one plane)
#define PE2 ((size_t)BB2*32*HWSZ)        // merged 32-ch plane set (both branches)

typedef unsigned short u16;
typedef unsigned long long ull;
typedef __attribute__((ext_vector_type(8))) short short8;
typedef __attribute__((ext_vector_type(2))) unsigned long long ull2;
typedef __attribute__((ext_vector_type(4))) float floatx4;

struct Ptrs16 { const float* p[16]; };

// ---------------- bf16 helpers ----------------
__device__ __forceinline__ u16 f2b(float f) {
  unsigned u = __builtin_bit_cast(unsigned, f);
  unsigned r = (u + 0x7fffu + ((u >> 16) & 1u)) >> 16;
  return (u16)r;
}
__device__ __forceinline__ float b2f(u16 h) {
  return __builtin_bit_cast(float, ((unsigned)h) << 16);
}

// ---------------- activation (eq. 33), delta = 0.01 ----------------
__device__ __forceinline__ float actf(float x) {
  float q = x*x*25.0f + 0.5f*x + 0.0025f;
  float r = fmaxf(x, 0.0f);
  return (fabsf(x) > 0.01f) ? r : q;
}
__device__ __forceinline__ float actdf(float x) {
  float q = x*50.0f + 0.5f;
  float r = (x > 0.0f) ? 1.0f : 0.0f;
  return (fabsf(x) > 0.01f) ? r : q;
}

// ---------------- weight prep, all 12 slots in one dispatch ----------------
// fp32 [o][c][9] -> bf16 [tap][nt][plane(r,i)][o16][c32], 18432 u16 per slot.
// -Wi is derived in-kernel by sign-bit XOR (R10-verified numerically exact).
__global__ void prep_all(Ptrs16 ps, u16* __restrict__ dst0) {
  const int rIdx[12] = {2,4,6,6,4,2,10,12,14,14,12,10};
  const int bwdF[12] = {0,0,0,1,1,1,0,0,0,1,1,1};
  int slot = blockIdx.x / 36;
  int idx = (blockIdx.x % 36)*256 + threadIdx.x;
  if (idx >= 9*32*32) return;
  const float* wr = ps.p[rIdx[slot]];
  const float* wi = ps.p[rIdx[slot]+1];
  u16* dst = dst0 + (size_t)slot*18432;
  int tap = idx >> 10; int rem = idx & 1023; int o = rem >> 5; int c = rem & 31;
  int s = bwdF[slot] ? ((c*32 + o)*9 + (8 - tap)) : ((o*32 + c)*9 + tap);
  float vr = wr[s], vi = wi[s];
  int nt = o >> 4, m = o & 15;
  size_t base = (((size_t)tap*2 + nt)*2*16 + (size_t)m)*32 + c;
  dst[base]       = f2b(vr);
  dst[base + 512] = f2b(vi);
}

// ---------------- MFMA complex conv 32->32, 3x3 SAME, implicit GEMM (R3-proven) ----
// NHWC bf16: addr = ((b*HH+y)*WW+x)*32 + ch, R at 0, I at +PE2. b in [0,16): branch=b>>3.
// Tile 32x4, 4 waves (wave=row), 2 m-segments, 256 threads. LDS 26112 B (6 blk/CU).
// T2 XOR swizzle byteaddr ^= ((B>>7)&7)<<4 at write AND read (R3-verified).
// OPERAND-SWAPPED MFMA: A=weights (M=och), B=pixels (N=px) -> D row=och, col=px.
// MODE: 1 act, 2 cmul by actdf(der)
template<int MODE>
__global__ __launch_bounds__(256, 6)
void conv_mfma(const u16* __restrict__ inb, const u16* __restrict__ wbA,
               const u16* __restrict__ wbB, u16* __restrict__ outb,
               const u16* __restrict__ derb,
               const float* __restrict__ thrA, const float* __restrict__ thrB)
{
  __shared__ alignas(128) u16 stg[2*6*34*32];   // 26112 B
  const int tid = threadIdx.x;
  const int lane = tid & 63, wv = tid >> 6;
  const int x0 = blockIdx.x * 32, y0 = blockIdx.y * 4, b = blockIdx.z;
  const u16* wb = (b < BB) ? wbA : wbB;
  const int m = lane & 15, q = lane >> 4;

  for (int j = tid; j < 1632; j += 256) {
    int prow = j / 136; int rem = j - prow*136;
    int col = rem >> 2, chq = rem & 3;
    int plane = prow / 6, row = prow - plane*6;
    int gy = y0 - 1 + row, gx = x0 - 1 + col;
    ull v0 = 0, v1 = 0;
    if (gy >= 0 && gy < HH && gx >= 0 && gx < WW) {
      const ull* src = (const ull*)(inb + (size_t)plane*PE2
                                    + (((size_t)b*HH + gy)*WW + gx)*32 + chq*8);
      v0 = src[0]; v1 = src[1];
    }
    int B = prow*2176 + col*64 + chq*16;
    B ^= ((B >> 7) & 7) << 4;
    ull* dst = (ull*)((char*)stg + B);
    dst[0] = v0; dst[1] = v1;
  }
  __syncthreads();

  floatx4 accr[2][2], acci[2][2];   // [seg][nt]
#pragma unroll
  for (int s = 0; s < 2; ++s)
#pragma unroll
    for (int nt = 0; nt < 2; ++nt) {
      accr[s][nt] = (floatx4){0.f,0.f,0.f,0.f};
      acci[s][nt] = (floatx4){0.f,0.f,0.f,0.f};
    }

#pragma unroll
  for (int tap = 0; tap < 9; ++tap) {
    const int ky = tap / 3, kx = tap - ky*3;
    short8 Pr[2], Pi[2];
#pragma unroll
    for (int s = 0; s < 2; ++s) {
      int col = s*16 + m + kx;
      int BR = ((wv + ky)*34 + col)*64 + q*16;
      int BI = BR + 13056;
      BR ^= ((BR >> 7) & 7) << 4;
      BI ^= ((BI >> 7) & 7) << 4;
      const ull* pR = (const ull*)((const char*)stg + BR);
      const ull* pI = (const ull*)((const char*)stg + BI);
      ull2 vr; vr.x = pR[0]; vr.y = pR[1];
      ull2 vi; vi.x = pI[0]; vi.y = pI[1];
      Pr[s] = __builtin_bit_cast(short8, vr);
      Pi[s] = __builtin_bit_cast(short8, vi);
    }
#pragma unroll
    for (int nt = 0; nt < 2; ++nt) {
      const u16* pw = wb + (size_t)(tap*2 + nt)*1024 + (size_t)m*32 + q*8;
      short8 Wr = *(const short8*)pw;
      short8 Wi = *(const short8*)(pw + 512);
      ull2 wx = __builtin_bit_cast(ull2, Wi);
      wx.x ^= 0x8000800080008000ULL;
      wx.y ^= 0x8000800080008000ULL;
      short8 nWi = __builtin_bit_cast(short8, wx);
#pragma unroll
      for (int s = 0; s < 2; ++s) {
        accr[s][nt] = __builtin_amdgcn_mfma_f32_16x16x32_bf16(Wr,  Pr[s], accr[s][nt], 0, 0, 0);
        accr[s][nt] = __builtin_amdgcn_mfma_f32_16x16x32_bf16(nWi, Pi[s], accr[s][nt], 0, 0, 0);
        acci[s][nt] = __builtin_amdgcn_mfma_f32_16x16x32_bf16(Wr,  Pi[s], acci[s][nt], 0, 0, 0);
        acci[s][nt] = __builtin_amdgcn_mfma_f32_16x16x32_bf16(Wi,  Pr[s], acci[s][nt], 0, 0, 0);
      }
    }
  }

  const int y = y0 + wv;
#pragma unroll
  for (int s = 0; s < 2; ++s) {
    int x = x0 + s*16 + m;
    bool ok = (x < WW);
    size_t pxbase = (((size_t)b*HH + y)*WW + x)*32;
#pragma unroll
    for (int nt = 0; nt < 2; ++nt) {
      size_t gb = pxbase + nt*16 + q*4;
      ull dR = 0, dI = 0;
      if constexpr (MODE == 2) {
        if (ok) { dR = *(const ull*)(derb + gb); dI = *(const ull*)(derb + PE2 + gb); }
      }
      ull vR = 0, vI = 0;
#pragma unroll
      for (int r = 0; r < 4; ++r) {
        float pr = accr[s][nt][r], pi = acci[s][nt][r];
        if constexpr (MODE == 1) { pr = actf(pr); pi = actf(pi); }
        if constexpr (MODE == 2) {
          float dr = actdf(b2f((u16)(dR >> (16*r))));
          float di = actdf(b2f((u16)(dI >> (16*r))));
          float nr = pr*dr - pi*di;
          pi = pr*di + pi*dr; pr = nr;
        }
        vR |= (ull)f2b(pr) << (16*r);
        vI |= (ull)f2b(pi) << (16*r);
      }
      if (ok) {
        *(ull*)(outb + gb)       = vR;
        *(ull*)(outb + PE2 + gb) = vI;
      }
    }
  }
  (void)thrA; (void)thrB;
}

// ---------------- FUSED: conv4-fwd + channel-norm + conv4T-bwd + actdf cmul (v2) ----
// R8 was correct but spilled (VGPR-array stash pRk/pIk + exR/exI + unrolled groups
// -> 1.67 GB scratch traffic, 447 us). v2: TWO disjoint LDS regions:
//   A = input rows y0-2..y0+5 x cols x0-2..x0+33, [plane][8][36][ch32] = 36864 B
//   B = intermediate 6x34, [plane][6][34][ch32] = 26112 B   (total 62976 B, 2 blk/CU)
// Fwd writes each group's normalized bf16 DIRECTLY to region B (disjoint from A, no
// mid-loop barrier needed); group loop is #pragma unroll 1 so only one fr/fi set is
// live (~80 VGPR, no spill). Epilogue reads the actdf derivative straight from the
// still-intact region A after the bwd pass. R7 boundary-zero fix retained.
// XOR swizzle ^((B>>7)&7)<<4 on every LDS byte address (both regions, 128B-aligned).
__global__ __launch_bounds__(256, 2)
void conv_f34(const u16* __restrict__ inb,
              const u16* __restrict__ wfA, const u16* __restrict__ wfB,
              const u16* __restrict__ wbA, const u16* __restrict__ wbB,
              u16* __restrict__ outb,
              const float* __restrict__ thrA, const float* __restrict__ thrB)
{
  __shared__ alignas(128) u16 stgA[2*8*36*32];   // 36864 B (input)
  __shared__ alignas(128) u16 stgB[2*6*34*32];   // 26112 B (intermediate)
  const int tid = threadIdx.x;
  const int lane = tid & 63, wv = tid >> 6;
  const int x0 = blockIdx.x*32, y0 = blockIdx.y*4, b = blockIdx.z;
  const u16* wf = (b < BB) ? wfA : wfB;
  const u16* wbk = (b < BB) ? wbA : wbB;
  const float thr = (b < BB ? thrA : thrB)[0];
  const int m = lane & 15, q = lane >> 4;

  // ---- stage input region A: 2304 16B chunks (plane8row x col36 x chq4) ----
  for (int j = tid; j < 2304; j += 256) {
    int prow = j / 144; int rem = j - prow*144;
    int col = rem >> 2, chq = rem & 3;
    int plane = prow >> 3, row = prow & 7;
    int gy = y0 - 2 + row, gx = x0 - 2 + col;
    ull v0 = 0, v1 = 0;
    if (gy >= 0 && gy < HH && gx >= 0 && gx < WW) {
      const ull* src = (const ull*)(inb + (size_t)plane*PE2
                                    + (((size_t)b*HH + gy)*WW + gx)*32 + chq*8);
      v0 = src[0]; v1 = src[1];
    }
    int B = (prow*36 + col)*64 + chq*16;
    B ^= ((B >> 7) & 7) << 4;
    ull* dst = (ull*)((char*)stgA + B);
    dst[0] = v0; dst[1] = v1;
  }
  __syncthreads();

  // ---- forward conv4 + normalize, 6x34 grid, write straight to region B ----
  // 204 px in 13 groups of 16; wave wv owns groups wv*3..wv*3+ng-1 (ng=3, wv3:4).
  // Lane (m,q): pixel p=g*16+m, och chunk q*4+r per nt. Norm over q via shfl 16,32.
  const int ng = (wv == 3) ? 4 : 3;
#pragma unroll 1
  for (int gi = 0; gi < ng; ++gi) {
    int g = wv*3 + gi;
    int p = g*16 + m;
    bool pv = (p < 204);
    int irow = pv ? (p / 34) : 0;
    int icol = pv ? (p - irow*34) : 0;
    floatx4 fr[2], fi[2];
#pragma unroll
    for (int nt = 0; nt < 2; ++nt) {
      fr[nt] = (floatx4){0.f,0.f,0.f,0.f};
      fi[nt] = (floatx4){0.f,0.f,0.f,0.f};
    }
#pragma unroll
    for (int tap = 0; tap < 9; ++tap) {
      int ky = tap/3, kx = tap - ky*3;
      int BA = ((irow + ky)*36 + (icol + kx))*64 + q*16;
      int BI = BA + 18432;
      BA ^= ((BA >> 7) & 7) << 4;
      BI ^= ((BI >> 7) & 7) << 4;
      const ull* pR = (const ull*)((const char*)stgA + BA);
      const ull* pI = (const ull*)((const char*)stgA + BI);
      ull2 vr; vr.x = pR[0]; vr.y = pR[1];
      ull2 vi; vi.x = pI[0]; vi.y = pI[1];
      short8 Pr = __builtin_bit_cast(short8, vr);
      short8 Pi = __builtin_bit_cast(short8, vi);
#pragma unroll
      for (int nt = 0; nt < 2; ++nt) {
        const u16* pw = wf + (size_t)(tap*2 + nt)*1024 + (size_t)m*32 + q*8;
        short8 Wr = *(const short8*)pw;
        short8 Wi = *(const short8*)(pw + 512);
        ull2 wx = __builtin_bit_cast(ull2, Wi);
        wx.x ^= 0x8000800080008000ULL;
        wx.y ^= 0x8000800080008000ULL;
        short8 nWi = __builtin_bit_cast(short8, wx);
        fr[nt] = __builtin_amdgcn_mfma_f32_16x16x32_bf16(Wr,  Pr, fr[nt], 0, 0, 0);
        fr[nt] = __builtin_amdgcn_mfma_f32_16x16x32_bf16(nWi, Pi, fr[nt], 0, 0, 0);
        fi[nt] = __builtin_amdgcn_mfma_f32_16x16x32_bf16(Wr,  Pi, fi[nt], 0, 0, 0);
        fi[nt] = __builtin_amdgcn_mfma_f32_16x16x32_bf16(Wi,  Pr, fi[nt], 0, 0, 0);
      }
    }
    // per-px 32-och norm: lanes {m,m+16,m+32,m+48} hold same pixel p
    float ss = 0.f;
#pragma unroll
    for (int nt = 0; nt < 2; ++nt)
#pragma unroll
      for (int r = 0; r < 4; ++r)
        ss += fr[nt][r]*fr[nt][r] + fi[nt][r]*fi[nt][r];
    ss += __shfl_xor(ss, 16, 64);
    ss += __shfl_xor(ss, 32, 64);
    float invn = 1.0f / fmaxf(sqrtf(ss), thr);
    // boundary-zero (R7 fix): out-of-image intermediate must be exactly 0
    int gyi = y0 - 1 + irow, gxi = x0 - 1 + icol;
    if (gyi < 0 || gyi >= HH || gxi < 0 || gxi >= WW) invn = 0.0f;
    if (pv) {
      int base = (irow*34 + icol)*64;
#pragma unroll
      for (int nt = 0; nt < 2; ++nt) {
        ull vR = 0, vI = 0;
#pragma unroll
        for (int r = 0; r < 4; ++r) {
          vR |= (ull)f2b(fr[nt][r]*invn) << (16*r);
          vI |= (ull)f2b(fi[nt][r]*invn) << (16*r);
        }
        int BA = base + nt*32 + q*8;
        int BI = BA + 13056;
        BA ^= ((BA >> 7) & 7) << 4;
        BI ^= ((BI >> 7) & 7) << 4;
        *(ull*)((char*)stgB + BA) = vR;
        *(ull*)((char*)stgB + BI) = vI;
      }
    }
  }
  __syncthreads();   // all region-B writes visible

  // ---- backward convT4 on region B, slot-3 weights (R3-verified loop) ----
  floatx4 accr[2][2], acci[2][2];
#pragma unroll
  for (int s = 0; s < 2; ++s)
#pragma unroll
    for (int nt = 0; nt < 2; ++nt) {
      accr[s][nt] = (floatx4){0.f,0.f,0.f,0.f};
      acci[s][nt] = (floatx4){0.f,0.f,0.f,0.f};
    }

#pragma unroll
  for (int tap = 0; tap < 9; ++tap) {
    const int ky = tap / 3, kx = tap - ky*3;
    short8 Pr[2], Pi[2];
#pragma unroll
    for (int s = 0; s < 2; ++s) {
      int col = s*16 + m + kx;
      int BR = ((wv + ky)*34 + col)*64 + q*16;
      int BI = BR + 13056;
      BR ^= ((BR >> 7) & 7) << 4;
      BI ^= ((BI >> 7) & 7) << 4;
      const ull* pR = (const ull*)((const char*)stgB + BR);
      const ull* pI = (const ull*)((const char*)stgB + BI);
      ull2 vr; vr.x = pR[0]; vr.y = pR[1];
      ull2 vi; vi.x = pI[0]; vi.y = pI[1];
      Pr[s] = __builtin_bit_cast(short8, vr);
      Pi[s] = __builtin_bit_cast(short8, vi);
    }
#pragma unroll
    for (int nt = 0; nt < 2; ++nt) {
      const u16* pw = wbk + (size_t)(tap*2 + nt)*1024 + (size_t)m*32 + q*8;
      short8 Wr = *(const short8*)pw;
      short8 Wi = *(const short8*)(pw + 512);
      ull2 wx = __builtin_bit_cast(ull2, Wi);
      wx.x ^= 0x8000800080008000ULL;
      wx.y ^= 0x8000800080008000ULL;
      short8 nWi = __builtin_bit_cast(short8, wx);
#pragma unroll
      for (int s = 0; s < 2; ++s) {
        accr[s][nt] = __builtin_amdgcn_mfma_f32_16x16x32_bf16(Wr,  Pr[s], accr[s][nt], 0, 0, 0);
        accr[s][nt] = __builtin_amdgcn_mfma_f32_16x16x32_bf16(nWi, Pi[s], accr[s][nt], 0, 0, 0);
        acci[s][nt] = __builtin_amdgcn_mfma_f32_16x16x32_bf16(Wr,  Pi[s], acci[s][nt], 0, 0, 0);
        acci[s][nt] = __builtin_amdgcn_mfma_f32_16x16x32_bf16(Wi,  Pr[s], acci[s][nt], 0, 0, 0);
      }
    }
  }

  // ---- epilogue: cmul by actdf(input from region A, still intact), store ----
  const int y = y0 + wv;
#pragma unroll
  for (int s = 0; s < 2; ++s) {
    int x = x0 + s*16 + m;
    bool ok = (x < WW);
    size_t pxbase = (((size_t)b*HH + y)*WW + x)*32;
#pragma unroll
    for (int nt = 0; nt < 2; ++nt) {
      int BA = ((2 + wv)*36 + (2 + s*16 + m))*64 + nt*32 + q*8;
      int BI = BA + 18432;
      BA ^= ((BA >> 7) & 7) << 4;
      BI ^= ((BI >> 7) & 7) << 4;
      ull dR = *(const ull*)((const char*)stgA + BA);
      ull dI = *(const ull*)((const char*)stgA + BI);
      size_t gb = pxbase + nt*16 + q*4;
      ull vR = 0, vI = 0;
#pragma unroll
      for (int r = 0; r < 4; ++r) {
        float pr = accr[s][nt][r], pi = acci[s][nt][r];
        float dr = actdf(b2f((u16)(dR >> (16*r))));
        float di = actdf(b2f((u16)(dI >> (16*r))));
        float nr = pr*dr - pi*di;
        pi = pr*di + pi*dr; pr = nr;
        vR |= (ull)f2b(pr) << (16*r);
        vI |= (ull)f2b(pi) << (16*r);
      }
      if (ok) {
        *(ull*)(outb + gb)       = vR;
        *(ull*)(outb + PE2 + gb) = vI;
      }
    }
  }
}

// ---------------- layer-1 forward: complex conv 1->32 + act, planar fp32 -> NHWC bf16
__global__ __launch_bounds__(256)
void l1fwd(const float* __restrict__ xall,
           const float* __restrict__ wrA, const float* __restrict__ wiA,
           const float* __restrict__ wrB, const float* __restrict__ wiB,
           u16* __restrict__ outb)
{
  __shared__ float hR[10][12], hI[10][12];
  __shared__ float wt[9][32][2];
  const int tid = threadIdx.x;
  const int og = tid & 3, px = tid >> 2;
  const int lx = px & 7, ly = px >> 3;
  const int x0 = blockIdx.x*8, y0 = blockIdx.y*8, b = blockIdx.z;
  const int branch = b >> 3, img = b & 7;
  const float* wr = branch ? wrB : wrA;
  const float* wi = branch ? wiB : wiA;
  const float* xp = xall + (size_t)branch*2*P1 + (size_t)img*HWSZ;

  for (int j = tid; j < 576; j += 256) {
    int tap = j >> 6; int rem = j & 63; int o = rem >> 1, ri = rem & 1;
    wt[tap][o][ri] = ri ? wi[o*9+tap] : wr[o*9+tap];
  }
  for (int j = tid; j < 200; j += 256) {
    int plane = j / 100; int pos = j - plane*100;
    int yy = pos / 10, xx = pos - yy*10;
    int gy = y0 - 1 + yy, gx = x0 - 1 + xx;
    float v = 0.f;
    if (gy >= 0 && gy < HH && gx >= 0 && gx < WW)
      v = xp[(size_t)plane*P1 + (size_t)gy*WW + gx];
    (plane ? hI : hR)[yy][xx] = v;
  }
  __syncthreads();

  float accR[8], accI[8];
#pragma unroll
  for (int o = 0; o < 8; ++o) { accR[o] = 0.f; accI[o] = 0.f; }
#pragma unroll
  for (int tap = 0; tap < 9; ++tap) {
    int ky = tap/3, kx = tap - ky*3;
    float ar = hR[ly+ky][lx+kx], ai = hI[ly+ky][lx+kx];
#pragma unroll
    for (int o = 0; o < 8; ++o) {
      float wrv = wt[tap][og*8+o][0], wiv = wt[tap][og*8+o][1];
      accR[o] += ar*wrv - ai*wiv;
      accI[o] += ar*wiv + ai*wrv;
    }
  }
  int gx = x0 + lx, gy = y0 + ly;
  if (gx < WW) {
    size_t base = (((size_t)b*HH + gy)*WW + gx)*32 + og*8;
    ull* dR = (ull*)(outb + base);
    ull* dI = (ull*)(outb + PE2 + base);
#pragma unroll
    for (int k = 0; k < 2; ++k) {
      ull vR = 0, vI = 0;
#pragma unroll
      for (int t = 0; t < 4; ++t) {
        vR |= (ull)f2b(actf(accR[k*4+t])) << (16*t);
        vI |= (ull)f2b(actf(accI[k*4+t])) << (16*t);
      }
      dR[k] = vR; dI[k] = vI;
    }
  }
}

// ---------------- layer-1 backward: complex convT 32->1, NHWC bf16 -> planar fp32 ----
__global__ __launch_bounds__(256)
void l1bwd(const u16* __restrict__ gb,
           const float* __restrict__ wrA, const float* __restrict__ wiA,
           const float* __restrict__ wrB, const float* __restrict__ wiB,
           float* __restrict__ outp)
{
  __shared__ alignas(16) u16 stg[2*100*32];   // [plane][pos10x10][ch32] = 12.5 KB
  __shared__ float wt[32][9][2];
  const int tid = threadIdx.x;
  const int cg = tid & 3, px = tid >> 2;
  const int lx = px & 7, ly = px >> 3;
  const int x0 = blockIdx.x*8, y0 = blockIdx.y*8, b = blockIdx.z;
  const int branch = b >> 3, img = b & 7;
  const float* wr = branch ? wrB : wrA;
  const float* wi = branch ? wiB : wiA;

  for (int j = tid; j < 576; j += 256) {
    int c = j / 18; int rem = j - c*18; int tap = rem >> 1, ri = rem & 1;
    wt[c][tap][ri] = (ri ? wi : wr)[c*9 + (8-tap)];
  }
  for (int j = tid; j < 800; j += 256) {
    int plane = j / 400; int rem = j - plane*400;
    int pos = rem >> 2, chq = rem & 3;
    int yy = pos / 10, xx = pos - yy*10;
    int gy = y0 - 1 + yy, gx = x0 - 1 + xx;
    ull v0 = 0, v1 = 0;
    if (gy >= 0 && gy < HH && gx >= 0 && gx < WW) {
      const ull* src = (const ull*)(gb + (size_t)plane*PE2
                                    + (((size_t)b*HH + gy)*WW + gx)*32 + chq*8);
      v0 = src[0]; v1 = src[1];
    }
    ull* dst = (ull*)&stg[((size_t)plane*100 + pos)*32 + chq*8];
    dst[0] = v0; dst[1] = v1;
  }
  __syncthreads();

  float gr = 0.f, gi = 0.f;
#pragma unroll
  for (int tap = 0; tap < 9; ++tap) {
    int ky = tap/3, kx = tap - ky*3;
    int pos = (ly+ky)*10 + (lx+kx);
    const ull* pR = (const ull*)&stg[(size_t)pos*32 + cg*8];
    const ull* pI = (const ull*)&stg[(100 + (size_t)pos)*32 + cg*8];
    ull r0 = pR[0], r1 = pR[1], i0 = pI[0], i1 = pI[1];
#pragma unroll
    for (int t = 0; t < 4; ++t) {
      int c = cg*8 + t;
      float ar = b2f((u16)(r0 >> (16*t))), ai = b2f((u16)(i0 >> (16*t)));
      float wrv = wt[c][tap][0], wiv = wt[c][tap][1];
      gr += ar*wrv - ai*wiv;
      gi += ar*wiv + ai*wrv;
    }
#pragma unroll
    for (int t = 0; t < 4; ++t) {
      int c = cg*8 + 4 + t;
      float ar = b2f((u16)(r1 >> (16*t))), ai = b2f((u16)(i1 >> (16*t)));
      float wrv = wt[c][tap][0], wiv = wt[c][tap][1];
      gr += ar*wrv - ai*wiv;
      gi += ar*wiv + ai*wrv;
    }
  }
  gr += __shfl_xor(gr, 1, 64); gr += __shfl_xor(gr, 2, 64);
  gi += __shfl_xor(gi, 1, 64); gi += __shfl_xor(gi, 2, 64);

  int gx = x0 + lx, gy = y0 + ly;
  if (cg == 0 && gx < WW) {
    size_t o2 = (size_t)branch*2*P1 + (size_t)img*HWSZ + (size_t)gy*WW + gx;
    outp[o2]      = gr;
    outp[P1 + o2] = gi;
  }
}

// ---------------- DFT machinery ----------------
__global__ void gen_dft2(float2* __restrict__ Mf, float2* __restrict__ Mi, int N) {
  int idx = blockIdx.x*256 + threadIdx.x;
  if (idx >= N*N) return;
  int r = idx / N, c = idx - r*N;
  long mm = ((long)r * (long)c) % N;
  double a = 2.0 * 3.14159265358979323846 * (double)mm / (double)N;
  double cs = cos(a), sn = sin(a);
  Mf[idx] = make_float2((float)cs, (float)(-sn));
  Mi[idx] = make_float2((float)(cs/N), (float)(sn/N));
}

__global__ void dft_row_planes(const float* __restrict__ xall,
                               float2* __restrict__ out, const float2* __restrict__ M) {
  int bh = blockIdx.x;
  int v = threadIdx.x; if (v >= WW) return;
  int b2 = bh / HH, h = bh - b2*HH;
  int branch = b2 >> 3, img = b2 & 7;
  const float* rowR = xall + (size_t)branch*2*P1 + (size_t)img*HWSZ + (size_t)h*WW;
  const float* rowI = rowR + P1;
  float ar = 0.f, ai = 0.f;
  for (int w = 0; w < WW; ++w) {
    float sr = rowR[w], si = rowI[w];
    float2 m = M[w*WW + v];
    ar += sr*m.x - si*m.y;
    ai += sr*m.y + si*m.x;
  }
  out[(size_t)bh*WW + v] = make_float2(ar, ai);
}

__global__ void dft_row_c(const float2* __restrict__ in, float2* __restrict__ out,
                          const float2* __restrict__ M) {
  int bh = blockIdx.x;
  int v = threadIdx.x; if (v >= WW) return;
  const float2* row = in + (size_t)bh*WW;
  float ar = 0.f, ai = 0.f;
  for (int w = 0; w < WW; ++w) {
    float2 s = row[w];
    float2 m = M[w*WW + v];
    ar += s.x*m.x - s.y*m.y;
    ai += s.x*m.y + s.y*m.x;
  }
  out[(size_t)bh*WW + v] = make_float2(ar, ai);
}

__global__ void dft_col_c(const float2* __restrict__ in, float2* __restrict__ out,
                          const float2* __restrict__ M) {
  int bu = blockIdx.x;
  int v = threadIdx.x; if (v >= WW) return;
  int b = bu / HH, u = bu - b*HH;
  const float2* base = in + (size_t)b*HWSZ;
  float ar = 0.f, ai = 0.f;
  for (int h = 0; h < HH; ++h) {
    float2 m = M[u*HH + h];
    float2 s = base[(size_t)h*WW + v];
    ar += s.x*m.x - s.y*m.y;
    ai += s.x*m.y + s.y*m.x;
  }
  out[(size_t)bu*WW + v] = make_float2(ar, ai);
}

__global__ void dft_col_mask(const float2* __restrict__ in, float2* __restrict__ out,
                             const float2* __restrict__ M, const float* __restrict__ mask) {
  int bu = blockIdx.x;
  int v = threadIdx.x; if (v >= WW) return;
  int b = bu / HH, u = bu - b*HH;
  const float2* base = in + (size_t)b*HWSZ;
  float ar = 0.f, ai = 0.f;
  for (int h = 0; h < HH; ++h) {
    float mk = mask[h*WW + v]; float mm = mk*mk;
    float2 m = M[u*HH + h];
    float2 s = base[(size_t)h*WW + v];
    float sr = s.x*mm, si = s.y*mm;
    ar += sr*m.x - si*m.y;
    ai += sr*m.y + si*m.x;
  }
  out[(size_t)bu*WW + v] = make_float2(ar, ai);
}

__global__ void dft_row_update(const float2* __restrict__ in, const float2* __restrict__ M,
                               const float2* __restrict__ ctall, const float* __restrict__ grp,
                               float* __restrict__ xall,
                               const float* __restrict__ al1, const float* __restrict__ al2,
                               const float* __restrict__ be1, const float* __restrict__ be2,
                               int phase) {
  int bh = blockIdx.x;
  int v = threadIdx.x; if (v >= WW) return;
  int b2 = bh / HH, h = bh - b2*HH;
  int branch = b2 >> 3, img = b2 & 7;
  const float2* row = in + (size_t)bh*WW;
  float ar = 0.f, ai = 0.f;
  for (int w = 0; w < WW; ++w) {
    float2 s = row[w];
    float2 m = M[w*WW + v];
    ar += s.x*m.x - s.y*m.y;
    ai += s.x*m.y + s.y*m.x;
  }
  float2 ct = ctall[(size_t)bh*WW + v];
  float a   = (branch ? al2 : al1)[phase];
  float bet = (branch ? be2 : be1)[phase];
  size_t xo = (size_t)branch*2*P1 + (size_t)img*HWSZ + (size_t)h*WW + v;
  xall[xo]      -= a*(ar - ct.x) + bet*grp[xo];
  xall[P1 + xo] -= a*(ai - ct.y) + bet*grp[P1 + xo];
}

// ---------------- small pointwise kernels ----------------
__global__ void maskk_m(const float* __restrict__ k1, const float* __restrict__ k2,
                        const float* __restrict__ mask, float2* __restrict__ t) {
  int i = blockIdx.x*256 + threadIdx.x;
  if (i >= (int)(2*P1)) return;
  int branch = i >= (int)P1;
  int ii = i - branch*(int)P1;
  int b = ii / HWSZ, p = ii - b*HWSZ;
  const float* k = branch ? k2 : k1;
  float m = mask[p];
  t[i] = make_float2(m * k[(size_t)b*2*HWSZ + p], m * k[(size_t)b*2*HWSZ + HWSZ + p]);
}

__global__ void unpack_m(const float* __restrict__ x1, const float* __restrict__ x2,
                         float* __restrict__ xall) {
  int i = blockIdx.x*256 + threadIdx.x;
  if (i >= (int)(2*P1)) return;
  int branch = i >= (int)P1;
  int ii = i - branch*(int)P1;
  int b = ii / HWSZ, p = ii - b*HWSZ;
  const float* src = branch ? x2 : x1;
  size_t dst = (size_t)branch*2*P1 + (size_t)b*HWSZ + p;
  xall[dst]      = src[(size_t)b*2*HWSZ + p];
  xall[P1 + dst] = src[(size_t)b*2*HWSZ + HWSZ + p];
}

__global__ void pack_kernel(const float* __restrict__ xall, float* __restrict__ out) {
  int i = blockIdx.x*256 + threadIdx.x;
  if (i >= (int)P1) return;
  int b = i / HWSZ, p = i - b*HWSZ;
  size_t ob = (size_t)b*4*HWSZ;
  size_t x1o = (size_t)b*HWSZ + p;
  size_t x2o = 2*P1 + x1o;
  out[ob + p]          = xall[x1o];
  out[ob + HWSZ + p]   = xall[P1 + x1o];
  out[ob + 2*HWSZ + p] = xall[x2o];
  out[ob + 3*HWSZ + p] = xall[P1 + x2o];
}

// ---------------- launch ----------------
extern "C" void kernel_launch(void* const* d_in, const int* in_sizes, int n_in,
                              void* d_out, int out_size, void* d_ws, size_t ws_size,
                              hipStream_t stream) {
  (void)in_sizes; (void)n_in; (void)out_size; (void)ws_size;
  const float* x1in = (const float*)d_in[0];
  const float* x2in = (const float*)d_in[1];
  const float* k1   = (const float*)d_in[2];
  const float* k2   = (const float*)d_in[3];
  const float* mask = (const float*)d_in[4];
  Ptrs16 cw;
  for (int i = 0; i < 16; ++i) cw.p[i] = (const float*)d_in[5+i];
  const float* thr1 = (const float*)d_in[21];
  const float* thr2 = (const float*)d_in[22];
  const float* al1  = (const float*)d_in[23];
  const float* al2  = (const float*)d_in[24];
  const float* be1  = (const float*)d_in[25];
  const float* be2  = (const float*)d_in[26];
  float* out = (float*)d_out;

  // ---- workspace: bf16 region then fp32 region ----
  u16* U = (u16*)d_ws;
  size_t uoff = 0;
  auto alloc_u = [&](size_t n){ u16* p = U + uoff; uoff += (n + 15) & ~(size_t)15; return p; };
  u16* act1 = alloc_u(2*PE2);
  u16* act2 = alloc_u(2*PE2);
  u16* act3 = alloc_u(2*PE2);
  u16* w4b  = alloc_u(2*PE2);
  u16* wp0  = alloc_u(12*18432);

  float* F = (float*)(U + uoff);
  size_t off = 0;
  auto alloc_f = [&](size_t n){ float* p = F + off; off += (n + 3) & ~(size_t)3; return p; };
  float*  xall = alloc_f(4*P1);                       // [branch][plane][P1]
  float*  grp  = alloc_f(4*P1);
  float2* t1   = (float2*)alloc_f(4*P1);              // [16][HWSZ] complex
  float2* t2   = (float2*)alloc_f(4*P1);
  float2* ctall= (float2*)alloc_f(4*P1);
  float2* EWf  = (float2*)alloc_f(2*(size_t)WW*WW);
  float2* EWi  = (float2*)alloc_f(2*(size_t)WW*WW);
  float2* EHf  = (float2*)alloc_f(2*(size_t)HH*HH);
  float2* EHi  = (float2*)alloc_f(2*(size_t)HH*HH);

  const dim3 MG(6, 40, BB2);      // conv: 32x4 tiles (3840 blocks)
  const dim3 LG(23, 20, BB2);     // l1 convs: 8x8 tiles
  const int NP1 = (int)((P1 + 255)/256);
  const int NP2 = (int)((2*P1 + 255)/256);
  const int DFTG = BB2*HH;        // 2560
  const int DFTB = 192;

  gen_dft2<<<(WW*WW+255)/256, 256, 0, stream>>>(EWf, EWi, WW);
  gen_dft2<<<(HH*HH+255)/256, 256, 0, stream>>>(EHf, EHi, HH);
  prep_all<<<12*36, 256, 0, stream>>>(cw, wp0);
  unpack_m<<<NP2, 256, 0, stream>>>(x1in, x2in, xall);

  // cterm = ifft2(mask*k), both branches
  maskk_m<<<NP2, 256, 0, stream>>>(k1, k2, mask, t1);
  dft_col_c<<<DFTG, DFTB, 0, stream>>>(t1, t2, EHi);
  dft_row_c<<<DFTG, DFTB, 0, stream>>>(t2, ctall, EWi);

  u16* WA[6]; u16* WB[6];
  for (int i = 0; i < 6; ++i) { WA[i] = wp0 + (size_t)i*18432; WB[i] = wp0 + (size_t)(6+i)*18432; }

  for (int ph = 0; ph < 3; ++ph) {
    // grad_r both branches
    l1fwd<<<LG, 256, 0, stream>>>(xall, cw.p[0], cw.p[1], cw.p[8], cw.p[9], act1);
    conv_mfma<1><<<MG, 256, 0, stream>>>(act1, WA[0], WB[0], act2, nullptr, nullptr, nullptr);
    conv_mfma<1><<<MG, 256, 0, stream>>>(act2, WA[1], WB[1], act3, nullptr, nullptr, nullptr);
    conv_f34<<<MG, 256, 0, stream>>>(act3, WA[2], WB[2], WA[3], WB[3], w4b, thr1, thr2);
    conv_mfma<2><<<MG, 256, 0, stream>>>(w4b,  WA[4], WB[4], act2, act2, nullptr, nullptr);
    conv_mfma<2><<<MG, 256, 0, stream>>>(act2, WA[5], WB[5], act1, act1, nullptr, nullptr);
    l1bwd<<<LG, 256, 0, stream>>>(act1, cw.p[0], cw.p[1], cw.p[8], cw.p[9], grp);
    // grad_f both branches + fused update
    dft_row_planes<<<DFTG, DFTB, 0, stream>>>(xall, t1, EWf);
    dft_col_c<<<DFTG, DFTB, 0, stream>>>(t1, t2, EHf);
    dft_col_mask<<<DFTG, DFTB, 0, stream>>>(t2, t1, EHi, mask);
    dft_row_update<<<DFTG, DFTB, 0, stream>>>(t1, EWi, ctall, grp, xall,
                                              al1, al2, be1, be2, ph);
  }

  pack_kernel<<<NP1, 256, 0, stream>>>(xall, out);
}

// Round 10
// 1978.254 us; speedup vs baseline: 2.0373x; 1.0432x over previous
//
#include <hip/hip_runtime.h>
#include <math.h>

#define HH 160
#define WW 180
#define HWSZ (HH*WW)
#define BB 8
#define BB2 16                           // both branches merged in z
#define P1 ((size_t)BB*HWSZ)             // 230400 (one branch, one plane)
#define PE2 ((size_t)BB2*32*HWSZ)        // merged 32-ch plane set (both branches)

typedef unsigned short u16;
typedef unsigned long long ull;
typedef __attribute__((ext_vector_type(8))) short short8;
typedef __attribute__((ext_vector_type(2))) unsigned long long ull2;
typedef __attribute__((ext_vector_type(4))) float floatx4;

struct Ptrs16 { const float* p[16]; };

// ---------------- async global->LDS (width=16), guide §5 / m97 pattern ----------------
typedef __attribute__((address_space(1))) const unsigned int* gas_t;
typedef __attribute__((address_space(3))) unsigned int* las_t;
__device__ __forceinline__ void async_cp16(const void* g, u16* l) {
  __builtin_amdgcn_global_load_lds((gas_t)g, (las_t)l, 16, 0, 0);
}

// ---------------- bf16 helpers ----------------
__device__ __forceinline__ u16 f2b(float f) {
  unsigned u = __builtin_bit_cast(unsigned, f);
  unsigned r = (u + 0x7fffu + ((u >> 16) & 1u)) >> 16;
  return (u16)r;
}
__device__ __forceinline__ float b2f(u16 h) {
  return __builtin_bit_cast(float, ((unsigned)h) << 16);
}

// ---------------- activation (eq. 33), delta = 0.01 ----------------
__device__ __forceinline__ float actf(float x) {
  float q = x*x*25.0f + 0.5f*x + 0.0025f;
  float r = fmaxf(x, 0.0f);
  return (fabsf(x) > 0.01f) ? r : q;
}
__device__ __forceinline__ float actdf(float x) {
  float q = x*50.0f + 0.5f;
  float r = (x > 0.0f) ? 1.0f : 0.0f;
  return (fabsf(x) > 0.01f) ? r : q;
}

// ---------------- zero scratch buffer for OOB async-copy sources ----------------
__global__ void zerok(u16* __restrict__ p) { p[threadIdx.x] = 0; }

// ---------------- weight prep, all 12 slots in one dispatch ----------------
__global__ void prep_all(Ptrs16 ps, u16* __restrict__ dst0) {
  const int rIdx[12] = {2,4,6,6,4,2,10,12,14,14,12,10};
  const int bwdF[12] = {0,0,0,1,1,1,0,0,0,1,1,1};
  int slot = blockIdx.x / 36;
  int idx = (blockIdx.x % 36)*256 + threadIdx.x;
  if (idx >= 9*32*32) return;
  const float* wr = ps.p[rIdx[slot]];
  const float* wi = ps.p[rIdx[slot]+1];
  u16* dst = dst0 + (size_t)slot*18432;
  int tap = idx >> 10; int rem = idx & 1023; int o = rem >> 5; int c = rem & 31;
  int s = bwdF[slot] ? ((c*32 + o)*9 + (8 - tap)) : ((o*32 + c)*9 + tap);
  float vr = wr[s], vi = wi[s];
  int nt = o >> 4, m = o & 15;
  size_t base = (((size_t)tap*2 + nt)*2*16 + (size_t)m)*32 + c;
  dst[base]       = f2b(vr);
  dst[base + 512] = f2b(vi);
}

// ---------------- MFMA complex conv 32->32, 3x3 SAME, implicit GEMM -----------------
// NHWC bf16: addr = ((b*HH+y)*WW+x)*32 + ch, R at 0, I at +PE2. b in [0,16): branch=b>>3.
// Tile 32x4, 4 waves, 2 m-segments, 256 threads.
// R9->R10: staging via ASYNC global_load_lds width=16 (no VGPR round-trip).
// Pre-swizzled source (m173): LDS dest is LINEAR (wave base + lane*16); lane j_dst
// fetches logical chunk j_src = j_dst ^ ((j_dst>>3)&7) (chunk-level form of the
// byte swizzle B ^= ((B>>7)&7)<<4, involution, bits3-5 invariant) -> LDS content
// identical to R3's explicit swizzled writes; reads unchanged.
// OOB/padding lanes source a zeroed 256B global buffer (per-lane src divergence OK).
// LDS padded 26112->28672 B (1792 chunks) so all 7x256 lanes have a valid dest
// (5 blk/CU, R0-proven equivalent). MODE: 1 act, 2 cmul by actdf(der).
template<int MODE>
__global__ __launch_bounds__(256, 5)
void conv_mfma(const u16* __restrict__ inb, const u16* __restrict__ wbA,
               const u16* __restrict__ wbB, u16* __restrict__ outb,
               const u16* __restrict__ derb, const u16* __restrict__ zb,
               const float* __restrict__ thrA, const float* __restrict__ thrB)
{
  __shared__ alignas(128) u16 stg[14336];   // 28672 B (26112 used + 2560 pad)
  const int tid = threadIdx.x;
  const int lane = tid & 63, wv = tid >> 6;
  const int x0 = blockIdx.x * 32, y0 = blockIdx.y * 4, b = blockIdx.z;
  const u16* wb = (b < BB) ? wbA : wbB;
  const int m = lane & 15, q = lane >> 4;

  // ---- async stage: 7 x 256 chunks, pre-swizzled source, linear LDS dest ----
  for (int k = 0; k < 7; ++k) {
    int jd = k*256 + tid;
    int js = jd ^ ((jd >> 3) & 7);
    const void* src = zb;
    if (jd < 1632) {
      int prow = js / 136; int rem = js - prow*136;
      int col = rem >> 2, chq = rem & 3;
      int plane = prow / 6, row = prow - plane*6;
      int gy = y0 - 1 + row, gx = x0 - 1 + col;
      if (gy >= 0 && gy < HH && gx >= 0 && gx < WW)
        src = inb + (size_t)plane*PE2 + (((size_t)b*HH + gy)*WW + gx)*32 + chq*8;
    }
    async_cp16(src, stg + (size_t)(k*256 + wv*64)*8);
  }
  __syncthreads();

  floatx4 accr[2][2], acci[2][2];   // [seg][nt]
#pragma unroll
  for (int s = 0; s < 2; ++s)
#pragma unroll
    for (int nt = 0; nt < 2; ++nt) {
      accr[s][nt] = (floatx4){0.f,0.f,0.f,0.f};
      acci[s][nt] = (floatx4){0.f,0.f,0.f,0.f};
    }

#pragma unroll
  for (int tap = 0; tap < 9; ++tap) {
    const int ky = tap / 3, kx = tap - ky*3;
    short8 Pr[2], Pi[2];
#pragma unroll
    for (int s = 0; s < 2; ++s) {
      int col = s*16 + m + kx;
      int BR = ((wv + ky)*34 + col)*64 + q*16;
      int BI = BR + 13056;
      BR ^= ((BR >> 7) & 7) << 4;
      BI ^= ((BI >> 7) & 7) << 4;
      const ull* pR = (const ull*)((const char*)stg + BR);
      const ull* pI = (const ull*)((const char*)stg + BI);
      ull2 vr; vr.x = pR[0]; vr.y = pR[1];
      ull2 vi; vi.x = pI[0]; vi.y = pI[1];
      Pr[s] = __builtin_bit_cast(short8, vr);
      Pi[s] = __builtin_bit_cast(short8, vi);
    }
#pragma unroll
    for (int nt = 0; nt < 2; ++nt) {
      const u16* pw = wb + (size_t)(tap*2 + nt)*1024 + (size_t)m*32 + q*8;
      short8 Wr = *(const short8*)pw;
      short8 Wi = *(const short8*)(pw + 512);
      ull2 wx = __builtin_bit_cast(ull2, Wi);
      wx.x ^= 0x8000800080008000ULL;
      wx.y ^= 0x8000800080008000ULL;
      short8 nWi = __builtin_bit_cast(short8, wx);
#pragma unroll
      for (int s = 0; s < 2; ++s) {
        accr[s][nt] = __builtin_amdgcn_mfma_f32_16x16x32_bf16(Wr,  Pr[s], accr[s][nt], 0, 0, 0);
        accr[s][nt] = __builtin_amdgcn_mfma_f32_16x16x32_bf16(nWi, Pi[s], accr[s][nt], 0, 0, 0);
        acci[s][nt] = __builtin_amdgcn_mfma_f32_16x16x32_bf16(Wr,  Pi[s], acci[s][nt], 0, 0, 0);
        acci[s][nt] = __builtin_amdgcn_mfma_f32_16x16x32_bf16(Wi,  Pr[s], acci[s][nt], 0, 0, 0);
      }
    }
  }

  const int y = y0 + wv;
#pragma unroll
  for (int s = 0; s < 2; ++s) {
    int x = x0 + s*16 + m;
    bool ok = (x < WW);
    size_t pxbase = (((size_t)b*HH + y)*WW + x)*32;
#pragma unroll
    for (int nt = 0; nt < 2; ++nt) {
      size_t gb = pxbase + nt*16 + q*4;
      ull dR = 0, dI = 0;
      if constexpr (MODE == 2) {
        if (ok) { dR = *(const ull*)(derb + gb); dI = *(const ull*)(derb + PE2 + gb); }
      }
      ull vR = 0, vI = 0;
#pragma unroll
      for (int r = 0; r < 4; ++r) {
        float pr = accr[s][nt][r], pi = acci[s][nt][r];
        if constexpr (MODE == 1) { pr = actf(pr); pi = actf(pi); }
        if constexpr (MODE == 2) {
          float dr = actdf(b2f((u16)(dR >> (16*r))));
          float di = actdf(b2f((u16)(dI >> (16*r))));
          float nr = pr*dr - pi*di;
          pi = pr*di + pi*dr; pr = nr;
        }
        vR |= (ull)f2b(pr) << (16*r);
        vI |= (ull)f2b(pi) << (16*r);
      }
      if (ok) {
        *(ull*)(outb + gb)       = vR;
        *(ull*)(outb + PE2 + gb) = vI;
      }
    }
  }
  (void)thrA; (void)thrB;
}

// ---------------- FUSED: conv4-fwd + channel-norm + conv4T-bwd + actdf cmul (v3) ----
// v2 + async global_load_lds staging of region A (2304 chunks = 9x256 exact,
// pre-swizzled source, linear dest). Region B unchanged (compute-written ds_write).
__global__ __launch_bounds__(256, 2)
void conv_f34(const u16* __restrict__ inb,
              const u16* __restrict__ wfA, const u16* __restrict__ wfB,
              const u16* __restrict__ wbA, const u16* __restrict__ wbB,
              u16* __restrict__ outb, const u16* __restrict__ zb,
              const float* __restrict__ thrA, const float* __restrict__ thrB)
{
  __shared__ alignas(128) u16 stgA[2*8*36*32];   // 36864 B (input)
  __shared__ alignas(128) u16 stgB[2*6*34*32];   // 26112 B (intermediate)
  const int tid = threadIdx.x;
  const int lane = tid & 63, wv = tid >> 6;
  const int x0 = blockIdx.x*32, y0 = blockIdx.y*4, b = blockIdx.z;
  const u16* wf = (b < BB) ? wfA : wfB;
  const u16* wbk = (b < BB) ? wbA : wbB;
  const float thr = (b < BB ? thrA : thrB)[0];
  const int m = lane & 15, q = lane >> 4;

  // ---- async stage region A: 9 x 256 chunks, pre-swizzled source ----
  for (int k = 0; k < 9; ++k) {
    int jd = k*256 + tid;
    int js = jd ^ ((jd >> 3) & 7);
    int prow = js / 144; int rem = js - prow*144;
    int col = rem >> 2, chq = rem & 3;
    int plane = prow >> 3, row = prow & 7;
    int gy = y0 - 2 + row, gx = x0 - 2 + col;
    const void* src = zb;
    if (gy >= 0 && gy < HH && gx >= 0 && gx < WW)
      src = inb + (size_t)plane*PE2 + (((size_t)b*HH + gy)*WW + gx)*32 + chq*8;
    async_cp16(src, stgA + (size_t)(k*256 + wv*64)*8);
  }
  __syncthreads();

  // ---- forward conv4 + normalize, 6x34 grid, write straight to region B ----
  const int ng = (wv == 3) ? 4 : 3;
#pragma unroll 1
  for (int gi = 0; gi < ng; ++gi) {
    int g = wv*3 + gi;
    int p = g*16 + m;
    bool pv = (p < 204);
    int irow = pv ? (p / 34) : 0;
    int icol = pv ? (p - irow*34) : 0;
    floatx4 fr[2], fi[2];
#pragma unroll
    for (int nt = 0; nt < 2; ++nt) {
      fr[nt] = (floatx4){0.f,0.f,0.f,0.f};
      fi[nt] = (floatx4){0.f,0.f,0.f,0.f};
    }
#pragma unroll
    for (int tap = 0; tap < 9; ++tap) {
      int ky = tap/3, kx = tap - ky*3;
      int BA = ((irow + ky)*36 + (icol + kx))*64 + q*16;
      int BI = BA + 18432;
      BA ^= ((BA >> 7) & 7) << 4;
      BI ^= ((BI >> 7) & 7) << 4;
      const ull* pR = (const ull*)((const char*)stgA + BA);
      const ull* pI = (const ull*)((const char*)stgA + BI);
      ull2 vr; vr.x = pR[0]; vr.y = pR[1];
      ull2 vi; vi.x = pI[0]; vi.y = pI[1];
      short8 Pr = __builtin_bit_cast(short8, vr);
      short8 Pi = __builtin_bit_cast(short8, vi);
#pragma unroll
      for (int nt = 0; nt < 2; ++nt) {
        const u16* pw = wf + (size_t)(tap*2 + nt)*1024 + (size_t)m*32 + q*8;
        short8 Wr = *(const short8*)pw;
        short8 Wi = *(const short8*)(pw + 512);
        ull2 wx = __builtin_bit_cast(ull2, Wi);
        wx.x ^= 0x8000800080008000ULL;
        wx.y ^= 0x8000800080008000ULL;
        short8 nWi = __builtin_bit_cast(short8, wx);
        fr[nt] = __builtin_amdgcn_mfma_f32_16x16x32_bf16(Wr,  Pr, fr[nt], 0, 0, 0);
        fr[nt] = __builtin_amdgcn_mfma_f32_16x16x32_bf16(nWi, Pi, fr[nt], 0, 0, 0);
        fi[nt] = __builtin_amdgcn_mfma_f32_16x16x32_bf16(Wr,  Pi, fi[nt], 0, 0, 0);
        fi[nt] = __builtin_amdgcn_mfma_f32_16x16x32_bf16(Wi,  Pr, fi[nt], 0, 0, 0);
      }
    }
    float ss = 0.f;
#pragma unroll
    for (int nt = 0; nt < 2; ++nt)
#pragma unroll
      for (int r = 0; r < 4; ++r)
        ss += fr[nt][r]*fr[nt][r] + fi[nt][r]*fi[nt][r];
    ss += __shfl_xor(ss, 16, 64);
    ss += __shfl_xor(ss, 32, 64);
    float invn = 1.0f / fmaxf(sqrtf(ss), thr);
    int gyi = y0 - 1 + irow, gxi = x0 - 1 + icol;
    if (gyi < 0 || gyi >= HH || gxi < 0 || gxi >= WW) invn = 0.0f;
    if (pv) {
      int base = (irow*34 + icol)*64;
#pragma unroll
      for (int nt = 0; nt < 2; ++nt) {
        ull vR = 0, vI = 0;
#pragma unroll
        for (int r = 0; r < 4; ++r) {
          vR |= (ull)f2b(fr[nt][r]*invn) << (16*r);
          vI |= (ull)f2b(fi[nt][r]*invn) << (16*r);
        }
        int BA = base + nt*32 + q*8;
        int BI = BA + 13056;
        BA ^= ((BA >> 7) & 7) << 4;
        BI ^= ((BI >> 7) & 7) << 4;
        *(ull*)((char*)stgB + BA) = vR;
        *(ull*)((char*)stgB + BI) = vI;
      }
    }
  }
  __syncthreads();

  // ---- backward convT4 on region B, slot-3 weights ----
  floatx4 accr[2][2], acci[2][2];
#pragma unroll
  for (int s = 0; s < 2; ++s)
#pragma unroll
    for (int nt = 0; nt < 2; ++nt) {
      accr[s][nt] = (floatx4){0.f,0.f,0.f,0.f};
      acci[s][nt] = (floatx4){0.f,0.f,0.f,0.f};
    }

#pragma unroll
  for (int tap = 0; tap < 9; ++tap) {
    const int ky = tap / 3, kx = tap - ky*3;
    short8 Pr[2], Pi[2];
#pragma unroll
    for (int s = 0; s < 2; ++s) {
      int col = s*16 + m + kx;
      int BR = ((wv + ky)*34 + col)*64 + q*16;
      int BI = BR + 13056;
      BR ^= ((BR >> 7) & 7) << 4;
      BI ^= ((BI >> 7) & 7) << 4;
      const ull* pR = (const ull*)((const char*)stgB + BR);
      const ull* pI = (const ull*)((const char*)stgB + BI);
      ull2 vr; vr.x = pR[0]; vr.y = pR[1];
      ull2 vi; vi.x = pI[0]; vi.y = pI[1];
      Pr[s] = __builtin_bit_cast(short8, vr);
      Pi[s] = __builtin_bit_cast(short8, vi);
    }
#pragma unroll
    for (int nt = 0; nt < 2; ++nt) {
      const u16* pw = wbk + (size_t)(tap*2 + nt)*1024 + (size_t)m*32 + q*8;
      short8 Wr = *(const short8*)pw;
      short8 Wi = *(const short8*)(pw + 512);
      ull2 wx = __builtin_bit_cast(ull2, Wi);
      wx.x ^= 0x8000800080008000ULL;
      wx.y ^= 0x8000800080008000ULL;
      short8 nWi = __builtin_bit_cast(short8, wx);
#pragma unroll
      for (int s = 0; s < 2; ++s) {
        accr[s][nt] = __builtin_amdgcn_mfma_f32_16x16x32_bf16(Wr,  Pr[s], accr[s][nt], 0, 0, 0);
        accr[s][nt] = __builtin_amdgcn_mfma_f32_16x16x32_bf16(nWi, Pi[s], accr[s][nt], 0, 0, 0);
        acci[s][nt] = __builtin_amdgcn_mfma_f32_16x16x32_bf16(Wr,  Pi[s], acci[s][nt], 0, 0, 0);
        acci[s][nt] = __builtin_amdgcn_mfma_f32_16x16x32_bf16(Wi,  Pr[s], acci[s][nt], 0, 0, 0);
      }
    }
  }

  // ---- epilogue: cmul by actdf(input from region A, still intact), store ----
  const int y = y0 + wv;
#pragma unroll
  for (int s = 0; s < 2; ++s) {
    int x = x0 + s*16 + m;
    bool ok = (x < WW);
    size_t pxbase = (((size_t)b*HH + y)*WW + x)*32;
#pragma unroll
    for (int nt = 0; nt < 2; ++nt) {
      int BA = ((2 + wv)*36 + (2 + s*16 + m))*64 + nt*32 + q*8;
      int BI = BA + 18432;
      BA ^= ((BA >> 7) & 7) << 4;
      BI ^= ((BI >> 7) & 7) << 4;
      ull dR = *(const ull*)((const char*)stgA + BA);
      ull dI = *(const ull*)((const char*)stgA + BI);
      size_t gb = pxbase + nt*16 + q*4;
      ull vR = 0, vI = 0;
#pragma unroll
      for (int r = 0; r < 4; ++r) {
        float pr = accr[s][nt][r], pi = acci[s][nt][r];
        float dr = actdf(b2f((u16)(dR >> (16*r))));
        float di = actdf(b2f((u16)(dI >> (16*r))));
        float nr = pr*dr - pi*di;
        pi = pr*di + pi*dr; pr = nr;
        vR |= (ull)f2b(pr) << (16*r);
        vI |= (ull)f2b(pi) << (16*r);
      }
      if (ok) {
        *(ull*)(outb + gb)       = vR;
        *(ull*)(outb + PE2 + gb) = vI;
      }
    }
  }
}

// ---------------- layer-1 forward: complex conv 1->32 + act, planar fp32 -> NHWC bf16
__global__ __launch_bounds__(256)
void l1fwd(const float* __restrict__ xall,
           const float* __restrict__ wrA, const float* __restrict__ wiA,
           const float* __restrict__ wrB, const float* __restrict__ wiB,
           u16* __restrict__ outb)
{
  __shared__ float hR[10][12], hI[10][12];
  __shared__ float wt[9][32][2];
  const int tid = threadIdx.x;
  const int og = tid & 3, px = tid >> 2;
  const int lx = px & 7, ly = px >> 3;
  const int x0 = blockIdx.x*8, y0 = blockIdx.y*8, b = blockIdx.z;
  const int branch = b >> 3, img = b & 7;
  const float* wr = branch ? wrB : wrA;
  const float* wi = branch ? wiB : wiA;
  const float* xp = xall + (size_t)branch*2*P1 + (size_t)img*HWSZ;

  for (int j = tid; j < 576; j += 256) {
    int tap = j >> 6; int rem = j & 63; int o = rem >> 1, ri = rem & 1;
    wt[tap][o][ri] = ri ? wi[o*9+tap] : wr[o*9+tap];
  }
  for (int j = tid; j < 200; j += 256) {
    int plane = j / 100; int pos = j - plane*100;
    int yy = pos / 10, xx = pos - yy*10;
    int gy = y0 - 1 + yy, gx = x0 - 1 + xx;
    float v = 0.f;
    if (gy >= 0 && gy < HH && gx >= 0 && gx < WW)
      v = xp[(size_t)plane*P1 + (size_t)gy*WW + gx];
    (plane ? hI : hR)[yy][xx] = v;
  }
  __syncthreads();

  float accR[8], accI[8];
#pragma unroll
  for (int o = 0; o < 8; ++o) { accR[o] = 0.f; accI[o] = 0.f; }
#pragma unroll
  for (int tap = 0; tap < 9; ++tap) {
    int ky = tap/3, kx = tap - ky*3;
    float ar = hR[ly+ky][lx+kx], ai = hI[ly+ky][lx+kx];
#pragma unroll
    for (int o = 0; o < 8; ++o) {
      float wrv = wt[tap][og*8+o][0], wiv = wt[tap][og*8+o][1];
      accR[o] += ar*wrv - ai*wiv;
      accI[o] += ar*wiv + ai*wrv;
    }
  }
  int gx = x0 + lx, gy = y0 + ly;
  if (gx < WW) {
    size_t base = (((size_t)b*HH + gy)*WW + gx)*32 + og*8;
    ull* dR = (ull*)(outb + base);
    ull* dI = (ull*)(outb + PE2 + base);
#pragma unroll
    for (int k = 0; k < 2; ++k) {
      ull vR = 0, vI = 0;
#pragma unroll
      for (int t = 0; t < 4; ++t) {
        vR |= (ull)f2b(actf(accR[k*4+t])) << (16*t);
        vI |= (ull)f2b(actf(accI[k*4+t])) << (16*t);
      }
      dR[k] = vR; dI[k] = vI;
    }
  }
}

// ---------------- layer-1 backward: complex convT 32->1, NHWC bf16 -> planar fp32 ----
__global__ __launch_bounds__(256)
void l1bwd(const u16* __restrict__ gb,
           const float* __restrict__ wrA, const float* __restrict__ wiA,
           const float* __restrict__ wrB, const float* __restrict__ wiB,
           float* __restrict__ outp)
{
  __shared__ alignas(16) u16 stg[2*100*32];   // [plane][pos10x10][ch32] = 12.5 KB
  __shared__ float wt[32][9][2];
  const int tid = threadIdx.x;
  const int cg = tid & 3, px = tid >> 2;
  const int lx = px & 7, ly = px >> 3;
  const int x0 = blockIdx.x*8, y0 = blockIdx.y*8, b = blockIdx.z;
  const int branch = b >> 3, img = b & 7;
  const float* wr = branch ? wrB : wrA;
  const float* wi = branch ? wiB : wiA;

  for (int j = tid; j < 576; j += 256) {
    int c = j / 18; int rem = j - c*18; int tap = rem >> 1, ri = rem & 1;
    wt[c][tap][ri] = (ri ? wi : wr)[c*9 + (8-tap)];
  }
  for (int j = tid; j < 800; j += 256) {
    int plane = j / 400; int rem = j - plane*400;
    int pos = rem >> 2, chq = rem & 3;
    int yy = pos / 10, xx = pos - yy*10;
    int gy = y0 - 1 + yy, gx = x0 - 1 + xx;
    ull v0 = 0, v1 = 0;
    if (gy >= 0 && gy < HH && gx >= 0 && gx < WW) {
      const ull* src = (const ull*)(gb + (size_t)plane*PE2
                                    + (((size_t)b*HH + gy)*WW + gx)*32 + chq*8);
      v0 = src[0]; v1 = src[1];
    }
    ull* dst = (ull*)&stg[((size_t)plane*100 + pos)*32 + chq*8];
    dst[0] = v0; dst[1] = v1;
  }
  __syncthreads();

  float gr = 0.f, gi = 0.f;
#pragma unroll
  for (int tap = 0; tap < 9; ++tap) {
    int ky = tap/3, kx = tap - ky*3;
    int pos = (ly+ky)*10 + (lx+kx);
    const ull* pR = (const ull*)&stg[(size_t)pos*32 + cg*8];
    const ull* pI = (const ull*)&stg[(100 + (size_t)pos)*32 + cg*8];
    ull r0 = pR[0], r1 = pR[1], i0 = pI[0], i1 = pI[1];
#pragma unroll
    for (int t = 0; t < 4; ++t) {
      int c = cg*8 + t;
      float ar = b2f((u16)(r0 >> (16*t))), ai = b2f((u16)(i0 >> (16*t)));
      float wrv = wt[c][tap][0], wiv = wt[c][tap][1];
      gr += ar*wrv - ai*wiv;
      gi += ar*wiv + ai*wrv;
    }
#pragma unroll
    for (int t = 0; t < 4; ++t) {
      int c = cg*8 + 4 + t;
      float ar = b2f((u16)(r1 >> (16*t))), ai = b2f((u16)(i1 >> (16*t)));
      float wrv = wt[c][tap][0], wiv = wt[c][tap][1];
      gr += ar*wrv - ai*wiv;
      gi += ar*wiv + ai*wrv;
    }
  }
  gr += __shfl_xor(gr, 1, 64); gr += __shfl_xor(gr, 2, 64);
  gi += __shfl_xor(gi, 1, 64); gi += __shfl_xor(gi, 2, 64);

  int gx = x0 + lx, gy = y0 + ly;
  if (cg == 0 && gx < WW) {
    size_t o2 = (size_t)branch*2*P1 + (size_t)img*HWSZ + (size_t)gy*WW + gx;
    outp[o2]      = gr;
    outp[P1 + o2] = gi;
  }
}

// ---------------- DFT machinery ----------------
__global__ void gen_dft2(float2* __restrict__ Mf, float2* __restrict__ Mi, int N) {
  int idx = blockIdx.x*256 + threadIdx.x;
  if (idx >= N*N) return;
  int r = idx / N, c = idx - r*N;
  long mm = ((long)r * (long)c) % N;
  double a = 2.0 * 3.14159265358979323846 * (double)mm / (double)N;
  double cs = cos(a), sn = sin(a);
  Mf[idx] = make_float2((float)cs, (float)(-sn));
  Mi[idx] = make_float2((float)(cs/N), (float)(sn/N));
}

__global__ void dft_row_planes(const float* __restrict__ xall,
                               float2* __restrict__ out, const float2* __restrict__ M) {
  int bh = blockIdx.x;
  int v = threadIdx.x; if (v >= WW) return;
  int b2 = bh / HH, h = bh - b2*HH;
  int branch = b2 >> 3, img = b2 & 7;
  const float* rowR = xall + (size_t)branch*2*P1 + (size_t)img*HWSZ + (size_t)h*WW;
  const float* rowI = rowR + P1;
  float ar = 0.f, ai = 0.f;
  for (int w = 0; w < WW; ++w) {
    float sr = rowR[w], si = rowI[w];
    float2 m = M[w*WW + v];
    ar += sr*m.x - si*m.y;
    ai += sr*m.y + si*m.x;
  }
  out[(size_t)bh*WW + v] = make_float2(ar, ai);
}

__global__ void dft_row_c(const float2* __restrict__ in, float2* __restrict__ out,
                          const float2* __restrict__ M) {
  int bh = blockIdx.x;
  int v = threadIdx.x; if (v >= WW) return;
  const float2* row = in + (size_t)bh*WW;
  float ar = 0.f, ai = 0.f;
  for (int w = 0; w < WW; ++w) {
    float2 s = row[w];
    float2 m = M[w*WW + v];
    ar += s.x*m.x - s.y*m.y;
    ai += s.x*m.y + s.y*m.x;
  }
  out[(size_t)bh*WW + v] = make_float2(ar, ai);
}

__global__ void dft_col_c(const float2* __restrict__ in, float2* __restrict__ out,
                          const float2* __restrict__ M) {
  int bu = blockIdx.x;
  int v = threadIdx.x; if (v >= WW) return;
  int b = bu / HH, u = bu - b*HH;
  const float2* base = in + (size_t)b*HWSZ;
  float ar = 0.f, ai = 0.f;
  for (int h = 0; h < HH; ++h) {
    float2 m = M[u*HH + h];
    float2 s = base[(size_t)h*WW + v];
    ar += s.x*m.x - s.y*m.y;
    ai += s.x*m.y + s.y*m.x;
  }
  out[(size_t)bu*WW + v] = make_float2(ar, ai);
}

__global__ void dft_col_mask(const float2* __restrict__ in, float2* __restrict__ out,
                             const float2* __restrict__ M, const float* __restrict__ mask) {
  int bu = blockIdx.x;
  int v = threadIdx.x; if (v >= WW) return;
  int b = bu / HH, u = bu - b*HH;
  const float2* base = in + (size_t)b*HWSZ;
  float ar = 0.f, ai = 0.f;
  for (int h = 0; h < HH; ++h) {
    float mk = mask[h*WW + v]; float mm = mk*mk;
    float2 m = M[u*HH + h];
    float2 s = base[(size_t)h*WW + v];
    float sr = s.x*mm, si = s.y*mm;
    ar += sr*m.x - si*m.y;
    ai += sr*m.y + si*m.x;
  }
  out[(size_t)bu*WW + v] = make_float2(ar, ai);
}

__global__ void dft_row_update(const float2* __restrict__ in, const float2* __restrict__ M,
                               const float2* __restrict__ ctall, const float* __restrict__ grp,
                               float* __restrict__ xall,
                               const float* __restrict__ al1, const float* __restrict__ al2,
                               const float* __restrict__ be1, const float* __restrict__ be2,
                               int phase) {
  int bh = blockIdx.x;
  int v = threadIdx.x; if (v >= WW) return;
  int b2 = bh / HH, h = bh - b2*HH;
  int branch = b2 >> 3, img = b2 & 7;
  const float2* row = in + (size_t)bh*WW;
  float ar = 0.f, ai = 0.f;
  for (int w = 0; w < WW; ++w) {
    float2 s = row[w];
    float2 m = M[w*WW + v];
    ar += s.x*m.x - s.y*m.y;
    ai += s.x*m.y + s.y*m.x;
  }
  float2 ct = ctall[(size_t)bh*WW + v];
  float a   = (branch ? al2 : al1)[phase];
  float bet = (branch ? be2 : be1)[phase];
  size_t xo = (size_t)branch*2*P1 + (size_t)img*HWSZ + (size_t)h*WW + v;
  xall[xo]      -= a*(ar - ct.x) + bet*grp[xo];
  xall[P1 + xo] -= a*(ai - ct.y) + bet*grp[P1 + xo];
}

// ---------------- small pointwise kernels ----------------
__global__ void maskk_m(const float* __restrict__ k1, const float* __restrict__ k2,
                        const float* __restrict__ mask, float2* __restrict__ t) {
  int i = blockIdx.x*256 + threadIdx.x;
  if (i >= (int)(2*P1)) return;
  int branch = i >= (int)P1;
  int ii = i - branch*(int)P1;
  int b = ii / HWSZ, p = ii - b*HWSZ;
  const float* k = branch ? k2 : k1;
  float m = mask[p];
  t[i] = make_float2(m * k[(size_t)b*2*HWSZ + p], m * k[(size_t)b*2*HWSZ + HWSZ + p]);
}

__global__ void unpack_m(const float* __restrict__ x1, const float* __restrict__ x2,
                         float* __restrict__ xall) {
  int i = blockIdx.x*256 + threadIdx.x;
  if (i >= (int)(2*P1)) return;
  int branch = i >= (int)P1;
  int ii = i - branch*(int)P1;
  int b = ii / HWSZ, p = ii - b*HWSZ;
  const float* src = branch ? x2 : x1;
  size_t dst = (size_t)branch*2*P1 + (size_t)b*HWSZ + p;
  xall[dst]      = src[(size_t)b*2*HWSZ + p];
  xall[P1 + dst] = src[(size_t)b*2*HWSZ + HWSZ + p];
}

__global__ void pack_kernel(const float* __restrict__ xall, float* __restrict__ out) {
  int i = blockIdx.x*256 + threadIdx.x;
  if (i >= (int)P1) return;
  int b = i / HWSZ, p = i - b*HWSZ;
  size_t ob = (size_t)b*4*HWSZ;
  size_t x1o = (size_t)b*HWSZ + p;
  size_t x2o = 2*P1 + x1o;
  out[ob + p]          = xall[x1o];
  out[ob + HWSZ + p]   = xall[P1 + x1o];
  out[ob + 2*HWSZ + p] = xall[x2o];
  out[ob + 3*HWSZ + p] = xall[P1 + x2o];
}

// ---------------- launch ----------------
extern "C" void kernel_launch(void* const* d_in, const int* in_sizes, int n_in,
                              void* d_out, int out_size, void* d_ws, size_t ws_size,
                              hipStream_t stream) {
  (void)in_sizes; (void)n_in; (void)out_size; (void)ws_size;
  const float* x1in = (const float*)d_in[0];
  const float* x2in = (const float*)d_in[1];
  const float* k1   = (const float*)d_in[2];
  const float* k2   = (const float*)d_in[3];
  const float* mask = (const float*)d_in[4];
  Ptrs16 cw;
  for (int i = 0; i < 16; ++i) cw.p[i] = (const float*)d_in[5+i];
  const float* thr1 = (const float*)d_in[21];
  const float* thr2 = (const float*)d_in[22];
  const float* al1  = (const float*)d_in[23];
  const float* al2  = (const float*)d_in[24];
  const float* be1  = (const float*)d_in[25];
  const float* be2  = (const float*)d_in[26];
  float* out = (float*)d_out;

  // ---- workspace: bf16 region then fp32 region ----
  u16* U = (u16*)d_ws;
  size_t uoff = 0;
  auto alloc_u = [&](size_t n){ u16* p = U + uoff; uoff += (n + 15) & ~(size_t)15; return p; };
  u16* act1 = alloc_u(2*PE2);
  u16* act2 = alloc_u(2*PE2);
  u16* act3 = alloc_u(2*PE2);
  u16* w4b  = alloc_u(2*PE2);
  u16* wp0  = alloc_u(12*18432);
  u16* zb   = alloc_u(128);           // 256B zeroed scratch for OOB async sources

  float* F = (float*)(U + uoff);
  size_t off = 0;
  auto alloc_f = [&](size_t n){ float* p = F + off; off += (n + 3) & ~(size_t)3; return p; };
  float*  xall = alloc_f(4*P1);                       // [branch][plane][P1]
  float*  grp  = alloc_f(4*P1);
  float2* t1   = (float2*)alloc_f(4*P1);              // [16][HWSZ] complex
  float2* t2   = (float2*)alloc_f(4*P1);
  float2* ctall= (float2*)alloc_f(4*P1);
  float2* EWf  = (float2*)alloc_f(2*(size_t)WW*WW);
  float2* EWi  = (float2*)alloc_f(2*(size_t)WW*WW);
  float2* EHf  = (float2*)alloc_f(2*(size_t)HH*HH);
  float2* EHi  = (float2*)alloc_f(2*(size_t)HH*HH);

  const dim3 MG(6, 40, BB2);      // conv: 32x4 tiles (3840 blocks)
  const dim3 LG(23, 20, BB2);     // l1 convs: 8x8 tiles
  const int NP1 = (int)((P1 + 255)/256);
  const int NP2 = (int)((2*P1 + 255)/256);
  const int DFTG = BB2*HH;        // 2560
  const int DFTB = 192;

  zerok<<<1, 128, 0, stream>>>(zb);
  gen_dft2<<<(WW*WW+255)/256, 256, 0, stream>>>(EWf, EWi, WW);
  gen_dft2<<<(HH*HH+255)/256, 256, 0, stream>>>(EHf, EHi, HH);
  prep_all<<<12*36, 256, 0, stream>>>(cw, wp0);
  unpack_m<<<NP2, 256, 0, stream>>>(x1in, x2in, xall);

  // cterm = ifft2(mask*k), both branches
  maskk_m<<<NP2, 256, 0, stream>>>(k1, k2, mask, t1);
  dft_col_c<<<DFTG, DFTB, 0, stream>>>(t1, t2, EHi);
  dft_row_c<<<DFTG, DFTB, 0, stream>>>(t2, ctall, EWi);

  u16* WA[6]; u16* WB[6];
  for (int i = 0; i < 6; ++i) { WA[i] = wp0 + (size_t)i*18432; WB[i] = wp0 + (size_t)(6+i)*18432; }

  for (int ph = 0; ph < 3; ++ph) {
    // grad_r both branches
    l1fwd<<<LG, 256, 0, stream>>>(xall, cw.p[0], cw.p[1], cw.p[8], cw.p[9], act1);
    conv_mfma<1><<<MG, 256, 0, stream>>>(act1, WA[0], WB[0], act2, nullptr, zb, nullptr, nullptr);
    conv_mfma<1><<<MG, 256, 0, stream>>>(act2, WA[1], WB[1], act3, nullptr, zb, nullptr, nullptr);
    conv_f34<<<MG, 256, 0, stream>>>(act3, WA[2], WB[2], WA[3], WB[3], w4b, zb, thr1, thr2);
    conv_mfma<2><<<MG, 256, 0, stream>>>(w4b,  WA[4], WB[4], act2, act2, zb, nullptr, nullptr);
    conv_mfma<2><<<MG, 256, 0, stream>>>(act2, WA[5], WB[5], act1, act1, zb, nullptr, nullptr);
    l1bwd<<<LG, 256, 0, stream>>>(act1, cw.p[0], cw.p[1], cw.p[8], cw.p[9], grp);
    // grad_f both branches + fused update
    dft_row_planes<<<DFTG, DFTB, 0, stream>>>(xall, t1, EWf);
    dft_col_c<<<DFTG, DFTB, 0, stream>>>(t1, t2, EHf);
    dft_col_mask<<<DFTG, DFTB, 0, stream>>>(t2, t1, EHi, mask);
    dft_row_update<<<DFTG, DFTB, 0, stream>>>(t1, EWi, ctall, grp, xall,
                                              al1, al2, be1, be2, ph);
  }

  pack_kernel<<<NP1, 256, 0, stream>>>(xall, out);
}

// Round 11
// 1870.133 us; speedup vs baseline: 2.1551x; 1.0578x over previous
//
#include <hip/hip_runtime.h>
#include <math.h>

#define HH 160
#define WW 180
#define HWSZ (HH*WW)
#define BB 8
#define BB2 16                           // both branches merged in z
#define P1 ((size_t)BB*HWSZ)             // 230400 (one branch, one plane)
#define PE2 ((size_t)BB2*32*HWSZ)        // merged 32-ch plane set (both branches)
#define RD 4                             // DFT rows/outputs per block (L2-traffic /4)

typedef unsigned short u16;
typedef unsigned long long ull;
typedef __attribute__((ext_vector_type(8))) short short8;
typedef __attribute__((ext_vector_type(2))) unsigned long long ull2;
typedef __attribute__((ext_vector_type(4))) float floatx4;

struct Ptrs16 { const float* p[16]; };

// ---------------- async global->LDS (width=16), guide §5 / m97 pattern ----------------
typedef __attribute__((address_space(1))) const unsigned int* gas_t;
typedef __attribute__((address_space(3))) unsigned int* las_t;
__device__ __forceinline__ void async_cp16(const void* g, u16* l) {
  __builtin_amdgcn_global_load_lds((gas_t)g, (las_t)l, 16, 0, 0);
}

// ---------------- bf16 helpers ----------------
__device__ __forceinline__ u16 f2b(float f) {
  unsigned u = __builtin_bit_cast(unsigned, f);
  unsigned r = (u + 0x7fffu + ((u >> 16) & 1u)) >> 16;
  return (u16)r;
}
__device__ __forceinline__ float b2f(u16 h) {
  return __builtin_bit_cast(float, ((unsigned)h) << 16);
}

// ---------------- activation (eq. 33), delta = 0.01 ----------------
__device__ __forceinline__ float actf(float x) {
  float q = x*x*25.0f + 0.5f*x + 0.0025f;
  float r = fmaxf(x, 0.0f);
  return (fabsf(x) > 0.01f) ? r : q;
}
__device__ __forceinline__ float actdf(float x) {
  float q = x*50.0f + 0.5f;
  float r = (x > 0.0f) ? 1.0f : 0.0f;
  return (fabsf(x) > 0.01f) ? r : q;
}

// ---------------- zero scratch buffer for OOB async-copy sources ----------------
__global__ void zerok(u16* __restrict__ p) { p[threadIdx.x] = 0; }

// ---------------- weight prep, all 12 slots in one dispatch ----------------
__global__ void prep_all(Ptrs16 ps, u16* __restrict__ dst0) {
  const int rIdx[12] = {2,4,6,6,4,2,10,12,14,14,12,10};
  const int bwdF[12] = {0,0,0,1,1,1,0,0,0,1,1,1};
  int slot = blockIdx.x / 36;
  int idx = (blockIdx.x % 36)*256 + threadIdx.x;
  if (idx >= 9*32*32) return;
  const float* wr = ps.p[rIdx[slot]];
  const float* wi = ps.p[rIdx[slot]+1];
  u16* dst = dst0 + (size_t)slot*18432;
  int tap = idx >> 10; int rem = idx & 1023; int o = rem >> 5; int c = rem & 31;
  int s = bwdF[slot] ? ((c*32 + o)*9 + (8 - tap)) : ((o*32 + c)*9 + tap);
  float vr = wr[s], vi = wi[s];
  int nt = o >> 4, m = o & 15;
  size_t base = (((size_t)tap*2 + nt)*2*16 + (size_t)m)*32 + c;
  dst[base]       = f2b(vr);
  dst[base + 512] = f2b(vi);
}

// ---------------- MFMA complex conv 32->32, 3x3 SAME, implicit GEMM (R10 async) ----
template<int MODE>
__global__ __launch_bounds__(256, 5)
void conv_mfma(const u16* __restrict__ inb, const u16* __restrict__ wbA,
               const u16* __restrict__ wbB, u16* __restrict__ outb,
               const u16* __restrict__ derb, const u16* __restrict__ zb,
               const float* __restrict__ thrA, const float* __restrict__ thrB)
{
  __shared__ alignas(128) u16 stg[14336];   // 28672 B (26112 used + 2560 pad)
  const int tid = threadIdx.x;
  const int lane = tid & 63, wv = tid >> 6;
  const int x0 = blockIdx.x * 32, y0 = blockIdx.y * 4, b = blockIdx.z;
  const u16* wb = (b < BB) ? wbA : wbB;
  const int m = lane & 15, q = lane >> 4;

  // ---- async stage: 7 x 256 chunks, pre-swizzled source, linear LDS dest ----
  for (int k = 0; k < 7; ++k) {
    int jd = k*256 + tid;
    int js = jd ^ ((jd >> 3) & 7);
    const void* src = zb;
    if (jd < 1632) {
      int prow = js / 136; int rem = js - prow*136;
      int col = rem >> 2, chq = rem & 3;
      int plane = prow / 6, row = prow - plane*6;
      int gy = y0 - 1 + row, gx = x0 - 1 + col;
      if (gy >= 0 && gy < HH && gx >= 0 && gx < WW)
        src = inb + (size_t)plane*PE2 + (((size_t)b*HH + gy)*WW + gx)*32 + chq*8;
    }
    async_cp16(src, stg + (size_t)(k*256 + wv*64)*8);
  }
  __syncthreads();

  floatx4 accr[2][2], acci[2][2];   // [seg][nt]
#pragma unroll
  for (int s = 0; s < 2; ++s)
#pragma unroll
    for (int nt = 0; nt < 2; ++nt) {
      accr[s][nt] = (floatx4){0.f,0.f,0.f,0.f};
      acci[s][nt] = (floatx4){0.f,0.f,0.f,0.f};
    }

#pragma unroll
  for (int tap = 0; tap < 9; ++tap) {
    const int ky = tap / 3, kx = tap - ky*3;
    short8 Pr[2], Pi[2];
#pragma unroll
    for (int s = 0; s < 2; ++s) {
      int col = s*16 + m + kx;
      int BR = ((wv + ky)*34 + col)*64 + q*16;
      int BI = BR + 13056;
      BR ^= ((BR >> 7) & 7) << 4;
      BI ^= ((BI >> 7) & 7) << 4;
      const ull* pR = (const ull*)((const char*)stg + BR);
      const ull* pI = (const ull*)((const char*)stg + BI);
      ull2 vr; vr.x = pR[0]; vr.y = pR[1];
      ull2 vi; vi.x = pI[0]; vi.y = pI[1];
      Pr[s] = __builtin_bit_cast(short8, vr);
      Pi[s] = __builtin_bit_cast(short8, vi);
    }
#pragma unroll
    for (int nt = 0; nt < 2; ++nt) {
      const u16* pw = wb + (size_t)(tap*2 + nt)*1024 + (size_t)m*32 + q*8;
      short8 Wr = *(const short8*)pw;
      short8 Wi = *(const short8*)(pw + 512);
      ull2 wx = __builtin_bit_cast(ull2, Wi);
      wx.x ^= 0x8000800080008000ULL;
      wx.y ^= 0x8000800080008000ULL;
      short8 nWi = __builtin_bit_cast(short8, wx);
#pragma unroll
      for (int s = 0; s < 2; ++s) {
        accr[s][nt] = __builtin_amdgcn_mfma_f32_16x16x32_bf16(Wr,  Pr[s], accr[s][nt], 0, 0, 0);
        accr[s][nt] = __builtin_amdgcn_mfma_f32_16x16x32_bf16(nWi, Pi[s], accr[s][nt], 0, 0, 0);
        acci[s][nt] = __builtin_amdgcn_mfma_f32_16x16x32_bf16(Wr,  Pi[s], acci[s][nt], 0, 0, 0);
        acci[s][nt] = __builtin_amdgcn_mfma_f32_16x16x32_bf16(Wi,  Pr[s], acci[s][nt], 0, 0, 0);
      }
    }
  }

  const int y = y0 + wv;
#pragma unroll
  for (int s = 0; s < 2; ++s) {
    int x = x0 + s*16 + m;
    bool ok = (x < WW);
    size_t pxbase = (((size_t)b*HH + y)*WW + x)*32;
#pragma unroll
    for (int nt = 0; nt < 2; ++nt) {
      size_t gb = pxbase + nt*16 + q*4;
      ull dR = 0, dI = 0;
      if constexpr (MODE == 2) {
        if (ok) { dR = *(const ull*)(derb + gb); dI = *(const ull*)(derb + PE2 + gb); }
      }
      ull vR = 0, vI = 0;
#pragma unroll
      for (int r = 0; r < 4; ++r) {
        float pr = accr[s][nt][r], pi = acci[s][nt][r];
        if constexpr (MODE == 1) { pr = actf(pr); pi = actf(pi); }
        if constexpr (MODE == 2) {
          float dr = actdf(b2f((u16)(dR >> (16*r))));
          float di = actdf(b2f((u16)(dI >> (16*r))));
          float nr = pr*dr - pi*di;
          pi = pr*di + pi*dr; pr = nr;
        }
        vR |= (ull)f2b(pr) << (16*r);
        vI |= (ull)f2b(pi) << (16*r);
      }
      if (ok) {
        *(ull*)(outb + gb)       = vR;
        *(ull*)(outb + PE2 + gb) = vI;
      }
    }
  }
  (void)thrA; (void)thrB;
}

// ---------------- FUSED: conv4-fwd + channel-norm + conv4T-bwd + actdf cmul (v3) ----
__global__ __launch_bounds__(256, 2)
void conv_f34(const u16* __restrict__ inb,
              const u16* __restrict__ wfA, const u16* __restrict__ wfB,
              const u16* __restrict__ wbA, const u16* __restrict__ wbB,
              u16* __restrict__ outb, const u16* __restrict__ zb,
              const float* __restrict__ thrA, const float* __restrict__ thrB)
{
  __shared__ alignas(128) u16 stgA[2*8*36*32];   // 36864 B (input)
  __shared__ alignas(128) u16 stgB[2*6*34*32];   // 26112 B (intermediate)
  const int tid = threadIdx.x;
  const int lane = tid & 63, wv = tid >> 6;
  const int x0 = blockIdx.x*32, y0 = blockIdx.y*4, b = blockIdx.z;
  const u16* wf = (b < BB) ? wfA : wfB;
  const u16* wbk = (b < BB) ? wbA : wbB;
  const float thr = (b < BB ? thrA : thrB)[0];
  const int m = lane & 15, q = lane >> 4;

  // ---- async stage region A: 9 x 256 chunks, pre-swizzled source ----
  for (int k = 0; k < 9; ++k) {
    int jd = k*256 + tid;
    int js = jd ^ ((jd >> 3) & 7);
    int prow = js / 144; int rem = js - prow*144;
    int col = rem >> 2, chq = rem & 3;
    int plane = prow >> 3, row = prow & 7;
    int gy = y0 - 2 + row, gx = x0 - 2 + col;
    const void* src = zb;
    if (gy >= 0 && gy < HH && gx >= 0 && gx < WW)
      src = inb + (size_t)plane*PE2 + (((size_t)b*HH + gy)*WW + gx)*32 + chq*8;
    async_cp16(src, stgA + (size_t)(k*256 + wv*64)*8);
  }
  __syncthreads();

  // ---- forward conv4 + normalize, 6x34 grid, write straight to region B ----
  const int ng = (wv == 3) ? 4 : 3;
#pragma unroll 1
  for (int gi = 0; gi < ng; ++gi) {
    int g = wv*3 + gi;
    int p = g*16 + m;
    bool pv = (p < 204);
    int irow = pv ? (p / 34) : 0;
    int icol = pv ? (p - irow*34) : 0;
    floatx4 fr[2], fi[2];
#pragma unroll
    for (int nt = 0; nt < 2; ++nt) {
      fr[nt] = (floatx4){0.f,0.f,0.f,0.f};
      fi[nt] = (floatx4){0.f,0.f,0.f,0.f};
    }
#pragma unroll
    for (int tap = 0; tap < 9; ++tap) {
      int ky = tap/3, kx = tap - ky*3;
      int BA = ((irow + ky)*36 + (icol + kx))*64 + q*16;
      int BI = BA + 18432;
      BA ^= ((BA >> 7) & 7) << 4;
      BI ^= ((BI >> 7) & 7) << 4;
      const ull* pR = (const ull*)((const char*)stgA + BA);
      const ull* pI = (const ull*)((const char*)stgA + BI);
      ull2 vr; vr.x = pR[0]; vr.y = pR[1];
      ull2 vi; vi.x = pI[0]; vi.y = pI[1];
      short8 Pr = __builtin_bit_cast(short8, vr);
      short8 Pi = __builtin_bit_cast(short8, vi);
#pragma unroll
      for (int nt = 0; nt < 2; ++nt) {
        const u16* pw = wf + (size_t)(tap*2 + nt)*1024 + (size_t)m*32 + q*8;
        short8 Wr = *(const short8*)pw;
        short8 Wi = *(const short8*)(pw + 512);
        ull2 wx = __builtin_bit_cast(ull2, Wi);
        wx.x ^= 0x8000800080008000ULL;
        wx.y ^= 0x8000800080008000ULL;
        short8 nWi = __builtin_bit_cast(short8, wx);
        fr[nt] = __builtin_amdgcn_mfma_f32_16x16x32_bf16(Wr,  Pr, fr[nt], 0, 0, 0);
        fr[nt] = __builtin_amdgcn_mfma_f32_16x16x32_bf16(nWi, Pi, fr[nt], 0, 0, 0);
        fi[nt] = __builtin_amdgcn_mfma_f32_16x16x32_bf16(Wr,  Pi, fi[nt], 0, 0, 0);
        fi[nt] = __builtin_amdgcn_mfma_f32_16x16x32_bf16(Wi,  Pr, fi[nt], 0, 0, 0);
      }
    }
    float ss = 0.f;
#pragma unroll
    for (int nt = 0; nt < 2; ++nt)
#pragma unroll
      for (int r = 0; r < 4; ++r)
        ss += fr[nt][r]*fr[nt][r] + fi[nt][r]*fi[nt][r];
    ss += __shfl_xor(ss, 16, 64);
    ss += __shfl_xor(ss, 32, 64);
    float invn = 1.0f / fmaxf(sqrtf(ss), thr);
    int gyi = y0 - 1 + irow, gxi = x0 - 1 + icol;
    if (gyi < 0 || gyi >= HH || gxi < 0 || gxi >= WW) invn = 0.0f;
    if (pv) {
      int base = (irow*34 + icol)*64;
#pragma unroll
      for (int nt = 0; nt < 2; ++nt) {
        ull vR = 0, vI = 0;
#pragma unroll
        for (int r = 0; r < 4; ++r) {
          vR |= (ull)f2b(fr[nt][r]*invn) << (16*r);
          vI |= (ull)f2b(fi[nt][r]*invn) << (16*r);
        }
        int BA = base + nt*32 + q*8;
        int BI = BA + 13056;
        BA ^= ((BA >> 7) & 7) << 4;
        BI ^= ((BI >> 7) & 7) << 4;
        *(ull*)((char*)stgB + BA) = vR;
        *(ull*)((char*)stgB + BI) = vI;
      }
    }
  }
  __syncthreads();

  // ---- backward convT4 on region B, slot-3 weights ----
  floatx4 accr[2][2], acci[2][2];
#pragma unroll
  for (int s = 0; s < 2; ++s)
#pragma unroll
    for (int nt = 0; nt < 2; ++nt) {
      accr[s][nt] = (floatx4){0.f,0.f,0.f,0.f};
      acci[s][nt] = (floatx4){0.f,0.f,0.f,0.f};
    }

#pragma unroll
  for (int tap = 0; tap < 9; ++tap) {
    const int ky = tap / 3, kx = tap - ky*3;
    short8 Pr[2], Pi[2];
#pragma unroll
    for (int s = 0; s < 2; ++s) {
      int col = s*16 + m + kx;
      int BR = ((wv + ky)*34 + col)*64 + q*16;
      int BI = BR + 13056;
      BR ^= ((BR >> 7) & 7) << 4;
      BI ^= ((BI >> 7) & 7) << 4;
      const ull* pR = (const ull*)((const char*)stgB + BR);
      const ull* pI = (const ull*)((const char*)stgB + BI);
      ull2 vr; vr.x = pR[0]; vr.y = pR[1];
      ull2 vi; vi.x = pI[0]; vi.y = pI[1];
      Pr[s] = __builtin_bit_cast(short8, vr);
      Pi[s] = __builtin_bit_cast(short8, vi);
    }
#pragma unroll
    for (int nt = 0; nt < 2; ++nt) {
      const u16* pw = wbk + (size_t)(tap*2 + nt)*1024 + (size_t)m*32 + q*8;
      short8 Wr = *(const short8*)pw;
      short8 Wi = *(const short8*)(pw + 512);
      ull2 wx = __builtin_bit_cast(ull2, Wi);
      wx.x ^= 0x8000800080008000ULL;
      wx.y ^= 0x8000800080008000ULL;
      short8 nWi = __builtin_bit_cast(short8, wx);
#pragma unroll
      for (int s = 0; s < 2; ++s) {
        accr[s][nt] = __builtin_amdgcn_mfma_f32_16x16x32_bf16(Wr,  Pr[s], accr[s][nt], 0, 0, 0);
        accr[s][nt] = __builtin_amdgcn_mfma_f32_16x16x32_bf16(nWi, Pi[s], accr[s][nt], 0, 0, 0);
        acci[s][nt] = __builtin_amdgcn_mfma_f32_16x16x32_bf16(Wr,  Pi[s], acci[s][nt], 0, 0, 0);
        acci[s][nt] = __builtin_amdgcn_mfma_f32_16x16x32_bf16(Wi,  Pr[s], acci[s][nt], 0, 0, 0);
      }
    }
  }

  // ---- epilogue: cmul by actdf(input from region A, still intact), store ----
  const int y = y0 + wv;
#pragma unroll
  for (int s = 0; s < 2; ++s) {
    int x = x0 + s*16 + m;
    bool ok = (x < WW);
    size_t pxbase = (((size_t)b*HH + y)*WW + x)*32;
#pragma unroll
    for (int nt = 0; nt < 2; ++nt) {
      int BA = ((2 + wv)*36 + (2 + s*16 + m))*64 + nt*32 + q*8;
      int BI = BA + 18432;
      BA ^= ((BA >> 7) & 7) << 4;
      BI ^= ((BI >> 7) & 7) << 4;
      ull dR = *(const ull*)((const char*)stgA + BA);
      ull dI = *(const ull*)((const char*)stgA + BI);
      size_t gb = pxbase + nt*16 + q*4;
      ull vR = 0, vI = 0;
#pragma unroll
      for (int r = 0; r < 4; ++r) {
        float pr = accr[s][nt][r], pi = acci[s][nt][r];
        float dr = actdf(b2f((u16)(dR >> (16*r))));
        float di = actdf(b2f((u16)(dI >> (16*r))));
        float nr = pr*dr - pi*di;
        pi = pr*di + pi*dr; pr = nr;
        vR |= (ull)f2b(pr) << (16*r);
        vI |= (ull)f2b(pi) << (16*r);
      }
      if (ok) {
        *(ull*)(outb + gb)       = vR;
        *(ull*)(outb + PE2 + gb) = vI;
      }
    }
  }
}

// ---------------- layer-1 forward: complex conv 1->32 + act, planar fp32 -> NHWC bf16
__global__ __launch_bounds__(256)
void l1fwd(const float* __restrict__ xall,
           const float* __restrict__ wrA, const float* __restrict__ wiA,
           const float* __restrict__ wrB, const float* __restrict__ wiB,
           u16* __restrict__ outb)
{
  __shared__ float hR[10][12], hI[10][12];
  __shared__ float wt[9][32][2];
  const int tid = threadIdx.x;
  const int og = tid & 3, px = tid >> 2;
  const int lx = px & 7, ly = px >> 3;
  const int x0 = blockIdx.x*8, y0 = blockIdx.y*8, b = blockIdx.z;
  const int branch = b >> 3, img = b & 7;
  const float* wr = branch ? wrB : wrA;
  const float* wi = branch ? wiB : wiA;
  const float* xp = xall + (size_t)branch*2*P1 + (size_t)img*HWSZ;

  for (int j = tid; j < 576; j += 256) {
    int tap = j >> 6; int rem = j & 63; int o = rem >> 1, ri = rem & 1;
    wt[tap][o][ri] = ri ? wi[o*9+tap] : wr[o*9+tap];
  }
  for (int j = tid; j < 200; j += 256) {
    int plane = j / 100; int pos = j - plane*100;
    int yy = pos / 10, xx = pos - yy*10;
    int gy = y0 - 1 + yy, gx = x0 - 1 + xx;
    float v = 0.f;
    if (gy >= 0 && gy < HH && gx >= 0 && gx < WW)
      v = xp[(size_t)plane*P1 + (size_t)gy*WW + gx];
    (plane ? hI : hR)[yy][xx] = v;
  }
  __syncthreads();

  float accR[8], accI[8];
#pragma unroll
  for (int o = 0; o < 8; ++o) { accR[o] = 0.f; accI[o] = 0.f; }
#pragma unroll
  for (int tap = 0; tap < 9; ++tap) {
    int ky = tap/3, kx = tap - ky*3;
    float ar = hR[ly+ky][lx+kx], ai = hI[ly+ky][lx+kx];
#pragma unroll
    for (int o = 0; o < 8; ++o) {
      float wrv = wt[tap][og*8+o][0], wiv = wt[tap][og*8+o][1];
      accR[o] += ar*wrv - ai*wiv;
      accI[o] += ar*wiv + ai*wrv;
    }
  }
  int gx = x0 + lx, gy = y0 + ly;
  if (gx < WW) {
    size_t base = (((size_t)b*HH + gy)*WW + gx)*32 + og*8;
    ull* dR = (ull*)(outb + base);
    ull* dI = (ull*)(outb + PE2 + base);
#pragma unroll
    for (int k = 0; k < 2; ++k) {
      ull vR = 0, vI = 0;
#pragma unroll
      for (int t = 0; t < 4; ++t) {
        vR |= (ull)f2b(actf(accR[k*4+t])) << (16*t);
        vI |= (ull)f2b(actf(accI[k*4+t])) << (16*t);
      }
      dR[k] = vR; dI[k] = vI;
    }
  }
}

// ---------------- layer-1 backward: complex convT 32->1, NHWC bf16 -> planar fp32 ----
__global__ __launch_bounds__(256)
void l1bwd(const u16* __restrict__ gb,
           const float* __restrict__ wrA, const float* __restrict__ wiA,
           const float* __restrict__ wrB, const float* __restrict__ wiB,
           float* __restrict__ outp)
{
  __shared__ alignas(16) u16 stg[2*100*32];   // [plane][pos10x10][ch32] = 12.5 KB
  __shared__ float wt[32][9][2];
  const int tid = threadIdx.x;
  const int cg = tid & 3, px = tid >> 2;
  const int lx = px & 7, ly = px >> 3;
  const int x0 = blockIdx.x*8, y0 = blockIdx.y*8, b = blockIdx.z;
  const int branch = b >> 3, img = b & 7;
  const float* wr = branch ? wrB : wrA;
  const float* wi = branch ? wiB : wiA;

  for (int j = tid; j < 576; j += 256) {
    int c = j / 18; int rem = j - c*18; int tap = rem >> 1, ri = rem & 1;
    wt[c][tap][ri] = (ri ? wi : wr)[c*9 + (8-tap)];
  }
  for (int j = tid; j < 800; j += 256) {
    int plane = j / 400; int rem = j - plane*400;
    int pos = rem >> 2, chq = rem & 3;
    int yy = pos / 10, xx = pos - yy*10;
    int gy = y0 - 1 + yy, gx = x0 - 1 + xx;
    ull v0 = 0, v1 = 0;
    if (gy >= 0 && gy < HH && gx >= 0 && gx < WW) {
      const ull* src = (const ull*)(gb + (size_t)plane*PE2
                                    + (((size_t)b*HH + gy)*WW + gx)*32 + chq*8);
      v0 = src[0]; v1 = src[1];
    }
    ull* dst = (ull*)&stg[((size_t)plane*100 + pos)*32 + chq*8];
    dst[0] = v0; dst[1] = v1;
  }
  __syncthreads();

  float gr = 0.f, gi = 0.f;
#pragma unroll
  for (int tap = 0; tap < 9; ++tap) {
    int ky = tap/3, kx = tap - ky*3;
    int pos = (ly+ky)*10 + (lx+kx);
    const ull* pR = (const ull*)&stg[(size_t)pos*32 + cg*8];
    const ull* pI = (const ull*)&stg[(100 + (size_t)pos)*32 + cg*8];
    ull r0 = pR[0], r1 = pR[1], i0 = pI[0], i1 = pI[1];
#pragma unroll
    for (int t = 0; t < 4; ++t) {
      int c = cg*8 + t;
      float ar = b2f((u16)(r0 >> (16*t))), ai = b2f((u16)(i0 >> (16*t)));
      float wrv = wt[c][tap][0], wiv = wt[c][tap][1];
      gr += ar*wrv - ai*wiv;
      gi += ar*wiv + ai*wrv;
    }
#pragma unroll
    for (int t = 0; t < 4; ++t) {
      int c = cg*8 + 4 + t;
      float ar = b2f((u16)(r1 >> (16*t))), ai = b2f((u16)(i1 >> (16*t)));
      float wrv = wt[c][tap][0], wiv = wt[c][tap][1];
      gr += ar*wrv - ai*wiv;
      gi += ar*wiv + ai*wrv;
    }
  }
  gr += __shfl_xor(gr, 1, 64); gr += __shfl_xor(gr, 2, 64);
  gi += __shfl_xor(gi, 1, 64); gi += __shfl_xor(gi, 2, 64);

  int gx = x0 + lx, gy = y0 + ly;
  if (cg == 0 && gx < WW) {
    size_t o2 = (size_t)branch*2*P1 + (size_t)img*HWSZ + (size_t)gy*WW + gx;
    outp[o2]      = gr;
    outp[P1 + o2] = gi;
  }
}

// ---------------- DFT machinery (R11: RD=4 outputs/block, L2 traffic /4) ----------------
__global__ void gen_dft2(float2* __restrict__ Mf, float2* __restrict__ Mi, int N) {
  int idx = blockIdx.x*256 + threadIdx.x;
  if (idx >= N*N) return;
  int r = idx / N, c = idx - r*N;
  long mm = ((long)r * (long)c) % N;
  double a = 2.0 * 3.14159265358979323846 * (double)mm / (double)N;
  double cs = cos(a), sn = sin(a);
  Mf[idx] = make_float2((float)cs, (float)(-sn));
  Mi[idx] = make_float2((float)(cs/N), (float)(sn/N));
}

// row-DFT from planar x: block = 4 consecutive bh rows (aligned, same b2), LDS-staged.
__global__ void dft_row_planes(const float* __restrict__ xall,
                               float2* __restrict__ out, const float2* __restrict__ M) {
  __shared__ float sR[RD][WW], sI[RD][WW];
  int bh0 = blockIdx.x * RD;
  int tid = threadIdx.x;
  for (int j = tid; j < RD*WW; j += 192) {
    int r = j / WW, w = j - r*WW;
    int bh = bh0 + r;
    int b2 = bh / HH, h = bh - b2*HH;
    int branch = b2 >> 3, img = b2 & 7;
    size_t base = (size_t)branch*2*P1 + (size_t)img*HWSZ + (size_t)h*WW + w;
    sR[r][w] = xall[base];
    sI[r][w] = xall[P1 + base];
  }
  __syncthreads();
  int v = tid; if (v >= WW) return;
  float ar[RD], ai[RD];
#pragma unroll
  for (int r = 0; r < RD; ++r) { ar[r] = 0.f; ai[r] = 0.f; }
  for (int w = 0; w < WW; ++w) {
    float2 m = M[w*WW + v];
#pragma unroll
    for (int r = 0; r < RD; ++r) {
      ar[r] += sR[r][w]*m.x - sI[r][w]*m.y;
      ai[r] += sR[r][w]*m.y + sI[r][w]*m.x;
    }
  }
#pragma unroll
  for (int r = 0; r < RD; ++r)
    out[(size_t)(bh0 + r)*WW + v] = make_float2(ar[r], ai[r]);
}

__global__ void dft_row_c(const float2* __restrict__ in, float2* __restrict__ out,
                          const float2* __restrict__ M) {
  __shared__ float2 s[RD][WW];
  int bh0 = blockIdx.x * RD;
  int tid = threadIdx.x;
  for (int j = tid; j < RD*WW; j += 192) {
    int r = j / WW, w = j - r*WW;
    s[r][w] = in[(size_t)(bh0 + r)*WW + w];
  }
  __syncthreads();
  int v = tid; if (v >= WW) return;
  float ar[RD], ai[RD];
#pragma unroll
  for (int r = 0; r < RD; ++r) { ar[r] = 0.f; ai[r] = 0.f; }
  for (int w = 0; w < WW; ++w) {
    float2 m = M[w*WW + v];
#pragma unroll
    for (int r = 0; r < RD; ++r) {
      ar[r] += s[r][w].x*m.x - s[r][w].y*m.y;
      ai[r] += s[r][w].x*m.y + s[r][w].y*m.x;
    }
  }
#pragma unroll
  for (int r = 0; r < RD; ++r)
    out[(size_t)(bh0 + r)*WW + v] = make_float2(ar[r], ai[r]);
}

// col-DFT: block = 4 consecutive u of one b; input panel read shared across the 4.
__global__ void dft_col_c(const float2* __restrict__ in, float2* __restrict__ out,
                          const float2* __restrict__ M) {
  int bu0 = blockIdx.x * RD;
  int v = threadIdx.x; if (v >= WW) return;
  int b = bu0 / HH, u0 = bu0 - b*HH;
  const float2* base = in + (size_t)b*HWSZ;
  float ar[RD], ai[RD];
#pragma unroll
  for (int r = 0; r < RD; ++r) { ar[r] = 0.f; ai[r] = 0.f; }
  for (int h = 0; h < HH; ++h) {
    float2 s = base[(size_t)h*WW + v];
#pragma unroll
    for (int r = 0; r < RD; ++r) {
      float2 m = M[(u0 + r)*HH + h];
      ar[r] += s.x*m.x - s.y*m.y;
      ai[r] += s.x*m.y + s.y*m.x;
    }
  }
#pragma unroll
  for (int r = 0; r < RD; ++r)
    out[(size_t)(bu0 + r)*WW + v] = make_float2(ar[r], ai[r]);
}

// col-iDFT with fused mask^2 (mask read amortized across 4 u)
__global__ void dft_col_mask(const float2* __restrict__ in, float2* __restrict__ out,
                             const float2* __restrict__ M, const float* __restrict__ mask) {
  int bu0 = blockIdx.x * RD;
  int v = threadIdx.x; if (v >= WW) return;
  int b = bu0 / HH, u0 = bu0 - b*HH;
  const float2* base = in + (size_t)b*HWSZ;
  float ar[RD], ai[RD];
#pragma unroll
  for (int r = 0; r < RD; ++r) { ar[r] = 0.f; ai[r] = 0.f; }
  for (int h = 0; h < HH; ++h) {
    float mk = mask[h*WW + v]; float mm = mk*mk;
    float2 s = base[(size_t)h*WW + v];
    float sr = s.x*mm, si = s.y*mm;
#pragma unroll
    for (int r = 0; r < RD; ++r) {
      float2 m = M[(u0 + r)*HH + h];
      ar[r] += sr*m.x - si*m.y;
      ai[r] += sr*m.y + si*m.x;
    }
  }
#pragma unroll
  for (int r = 0; r < RD; ++r)
    out[(size_t)(bu0 + r)*WW + v] = make_float2(ar[r], ai[r]);
}

// final row-iDFT fused with x update, 4 rows/block
__global__ void dft_row_update(const float2* __restrict__ in, const float2* __restrict__ M,
                               const float2* __restrict__ ctall, const float* __restrict__ grp,
                               float* __restrict__ xall,
                               const float* __restrict__ al1, const float* __restrict__ al2,
                               const float* __restrict__ be1, const float* __restrict__ be2,
                               int phase) {
  __shared__ float2 s[RD][WW];
  int bh0 = blockIdx.x * RD;
  int tid = threadIdx.x;
  for (int j = tid; j < RD*WW; j += 192) {
    int r = j / WW, w = j - r*WW;
    s[r][w] = in[(size_t)(bh0 + r)*WW + w];
  }
  __syncthreads();
  int v = tid; if (v >= WW) return;
  float ar[RD], ai[RD];
#pragma unroll
  for (int r = 0; r < RD; ++r) { ar[r] = 0.f; ai[r] = 0.f; }
  for (int w = 0; w < WW; ++w) {
    float2 m = M[w*WW + v];
#pragma unroll
    for (int r = 0; r < RD; ++r) {
      ar[r] += s[r][w].x*m.x - s[r][w].y*m.y;
      ai[r] += s[r][w].x*m.y + s[r][w].y*m.x;
    }
  }
  int b2 = bh0 / HH;              // 4-aligned blocks never cross b2 (160 % 4 == 0)
  int branch = b2 >> 3, img = b2 & 7;
  float a   = (branch ? al2 : al1)[phase];
  float bet = (branch ? be2 : be1)[phase];
#pragma unroll
  for (int r = 0; r < RD; ++r) {
    int bh = bh0 + r; int h = bh - b2*HH;
    float2 ct = ctall[(size_t)bh*WW + v];
    size_t xo = (size_t)branch*2*P1 + (size_t)img*HWSZ + (size_t)h*WW + v;
    xall[xo]      -= a*(ar[r] - ct.x) + bet*grp[xo];
    xall[P1 + xo] -= a*(ai[r] - ct.y) + bet*grp[P1 + xo];
  }
}

// ---------------- small pointwise kernels ----------------
__global__ void maskk_m(const float* __restrict__ k1, const float* __restrict__ k2,
                        const float* __restrict__ mask, float2* __restrict__ t) {
  int i = blockIdx.x*256 + threadIdx.x;
  if (i >= (int)(2*P1)) return;
  int branch = i >= (int)P1;
  int ii = i - branch*(int)P1;
  int b = ii / HWSZ, p = ii - b*HWSZ;
  const float* k = branch ? k2 : k1;
  float m = mask[p];
  t[i] = make_float2(m * k[(size_t)b*2*HWSZ + p], m * k[(size_t)b*2*HWSZ + HWSZ + p]);
}

__global__ void unpack_m(const float* __restrict__ x1, const float* __restrict__ x2,
                         float* __restrict__ xall) {
  int i = blockIdx.x*256 + threadIdx.x;
  if (i >= (int)(2*P1)) return;
  int branch = i >= (int)P1;
  int ii = i - branch*(int)P1;
  int b = ii / HWSZ, p = ii - b*HWSZ;
  const float* src = branch ? x2 : x1;
  size_t dst = (size_t)branch*2*P1 + (size_t)b*HWSZ + p;
  xall[dst]      = src[(size_t)b*2*HWSZ + p];
  xall[P1 + dst] = src[(size_t)b*2*HWSZ + HWSZ + p];
}

__global__ void pack_kernel(const float* __restrict__ xall, float* __restrict__ out) {
  int i = blockIdx.x*256 + threadIdx.x;
  if (i >= (int)P1) return;
  int b = i / HWSZ, p = i - b*HWSZ;
  size_t ob = (size_t)b*4*HWSZ;
  size_t x1o = (size_t)b*HWSZ + p;
  size_t x2o = 2*P1 + x1o;
  out[ob + p]          = xall[x1o];
  out[ob + HWSZ + p]   = xall[P1 + x1o];
  out[ob + 2*HWSZ + p] = xall[x2o];
  out[ob + 3*HWSZ + p] = xall[P1 + x2o];
}

// ---------------- launch ----------------
extern "C" void kernel_launch(void* const* d_in, const int* in_sizes, int n_in,
                              void* d_out, int out_size, void* d_ws, size_t ws_size,
                              hipStream_t stream) {
  (void)in_sizes; (void)n_in; (void)out_size; (void)ws_size;
  const float* x1in = (const float*)d_in[0];
  const float* x2in = (const float*)d_in[1];
  const float* k1   = (const float*)d_in[2];
  const float* k2   = (const float*)d_in[3];
  const float* mask = (const float*)d_in[4];
  Ptrs16 cw;
  for (int i = 0; i < 16; ++i) cw.p[i] = (const float*)d_in[5+i];
  const float* thr1 = (const float*)d_in[21];
  const float* thr2 = (const float*)d_in[22];
  const float* al1  = (const float*)d_in[23];
  const float* al2  = (const float*)d_in[24];
  const float* be1  = (const float*)d_in[25];
  const float* be2  = (const float*)d_in[26];
  float* out = (float*)d_out;

  // ---- workspace: bf16 region then fp32 region ----
  u16* U = (u16*)d_ws;
  size_t uoff = 0;
  auto alloc_u = [&](size_t n){ u16* p = U + uoff; uoff += (n + 15) & ~(size_t)15; return p; };
  u16* act1 = alloc_u(2*PE2);
  u16* act2 = alloc_u(2*PE2);
  u16* act3 = alloc_u(2*PE2);
  u16* w4b  = alloc_u(2*PE2);
  u16* wp0  = alloc_u(12*18432);
  u16* zb   = alloc_u(128);           // 256B zeroed scratch for OOB async sources

  float* F = (float*)(U + uoff);
  size_t off = 0;
  auto alloc_f = [&](size_t n){ float* p = F + off; off += (n + 3) & ~(size_t)3; return p; };
  float*  xall = alloc_f(4*P1);                       // [branch][plane][P1]
  float*  grp  = alloc_f(4*P1);
  float2* t1   = (float2*)alloc_f(4*P1);              // [16][HWSZ] complex
  float2* t2   = (float2*)alloc_f(4*P1);
  float2* ctall= (float2*)alloc_f(4*P1);
  float2* EWf  = (float2*)alloc_f(2*(size_t)WW*WW);
  float2* EWi  = (float2*)alloc_f(2*(size_t)WW*WW);
  float2* EHf  = (float2*)alloc_f(2*(size_t)HH*HH);
  float2* EHi  = (float2*)alloc_f(2*(size_t)HH*HH);

  const dim3 MG(6, 40, BB2);      // conv: 32x4 tiles (3840 blocks)
  const dim3 LG(23, 20, BB2);     // l1 convs: 8x8 tiles
  const int NP1 = (int)((P1 + 255)/256);
  const int NP2 = (int)((2*P1 + 255)/256);
  const int DFTG2 = BB2*HH/RD;    // 640 blocks, 4 rows each
  const int DFTB = 192;

  zerok<<<1, 128, 0, stream>>>(zb);
  gen_dft2<<<(WW*WW+255)/256, 256, 0, stream>>>(EWf, EWi, WW);
  gen_dft2<<<(HH*HH+255)/256, 256, 0, stream>>>(EHf, EHi, HH);
  prep_all<<<12*36, 256, 0, stream>>>(cw, wp0);
  unpack_m<<<NP2, 256, 0, stream>>>(x1in, x2in, xall);

  // cterm = ifft2(mask*k), both branches
  maskk_m<<<NP2, 256, 0, stream>>>(k1, k2, mask, t1);
  dft_col_c<<<DFTG2, DFTB, 0, stream>>>(t1, t2, EHi);
  dft_row_c<<<DFTG2, DFTB, 0, stream>>>(t2, ctall, EWi);

  u16* WA[6]; u16* WB[6];
  for (int i = 0; i < 6; ++i) { WA[i] = wp0 + (size_t)i*18432; WB[i] = wp0 + (size_t)(6+i)*18432; }

  for (int ph = 0; ph < 3; ++ph) {
    // grad_r both branches
    l1fwd<<<LG, 256, 0, stream>>>(xall, cw.p[0], cw.p[1], cw.p[8], cw.p[9], act1);
    conv_mfma<1><<<MG, 256, 0, stream>>>(act1, WA[0], WB[0], act2, nullptr, zb, nullptr, nullptr);
    conv_mfma<1><<<MG, 256, 0, stream>>>(act2, WA[1], WB[1], act3, nullptr, zb, nullptr, nullptr);
    conv_f34<<<MG, 256, 0, stream>>>(act3, WA[2], WB[2], WA[3], WB[3], w4b, zb, thr1, thr2);
    conv_mfma<2><<<MG, 256, 0, stream>>>(w4b,  WA[4], WB[4], act2, act2, zb, nullptr, nullptr);
    conv_mfma<2><<<MG, 256, 0, stream>>>(act2, WA[5], WB[5], act1, act1, zb, nullptr, nullptr);
    l1bwd<<<LG, 256, 0, stream>>>(act1, cw.p[0], cw.p[1], cw.p[8], cw.p[9], grp);
    // grad_f both branches + fused update
    dft_row_planes<<<DFTG2, DFTB, 0, stream>>>(xall, t1, EWf);
    dft_col_c<<<DFTG2, DFTB, 0, stream>>>(t1, t2, EHf);
    dft_col_mask<<<DFTG2, DFTB, 0, stream>>>(t2, t1, EHi, mask);
    dft_row_update<<<DFTG2, DFTB, 0, stream>>>(t1, EWi, ctall, grp, xall,
                                               al1, al2, be1, be2, ph);
  }

  pack_kernel<<<NP1, 256, 0, stream>>>(xall, out);
}